// Round 1
// baseline (149.018 us; speedup 1.0000x reference)
//
#include <hip/hip_runtime.h>
#include <hip/hip_bf16.h>

// MHSA: x(2,512,2048) f32, 8 heads x 64. All heavy math in bf16 MFMA 16x16x32.
// Pipeline: xpose -> wconv -> gemm_bt<0>(QK) -> gemm_bt<1>(V) -> attn -> gemm_bt<2>(out)

typedef __attribute__((ext_vector_type(8))) short short8;   // 8 bf16 = 4 VGPR (MFMA A/B frag)
typedef __attribute__((ext_vector_type(4))) short short4v;  // 4 bf16 (8B store)
typedef __attribute__((ext_vector_type(4))) float f32x4;    // MFMA C/D frag

#define DEV static __device__ __forceinline__

DEV short f2bf(float f) {  // fp32 -> bf16 RNE
  union { float f; unsigned u; } v; v.f = f;
  unsigned r = (v.u + 0x7FFFu + ((v.u >> 16) & 1u)) >> 16;
  return (short)r;
}

DEV void gload_lds16(const void* g, void* l) {
  // wave-uniform LDS base; HW writes lane*16B
  __builtin_amdgcn_global_load_lds((const __attribute__((address_space(1))) void*)g,
                                   (__attribute__((address_space(3))) void*)l, 16, 0, 0);
}

// ---------------- pass 0a: x (B,512,2048) f32 -> XT[(b*2048+s)][512] bf16 ----------------
__global__ __launch_bounds__(256) void xpose_k(const float* __restrict__ x, short* __restrict__ xt) {
  __shared__ float tile[32][33];
  const int b = blockIdx.z;
  const int s0 = blockIdx.x * 32, c0 = blockIdx.y * 32;
  const int tl = threadIdx.x & 31, tr = threadIdx.x >> 5;  // tr 0..7
  const float* src = x + ((size_t)b * 512 + c0) * 2048 + s0;
#pragma unroll
  for (int i = 0; i < 4; ++i)
    tile[tr + i * 8][tl] = src[(size_t)(tr + i * 8) * 2048 + tl];  // tile[c][s]
  __syncthreads();
  short* dst = xt + ((size_t)b * 2048 + s0) * 512 + c0;
#pragma unroll
  for (int i = 0; i < 4; ++i) {
    const int s = tr + i * 8;
    dst[(size_t)s * 512 + tl] = f2bf(tile[tl][s]);
  }
}

// ---------------- pass 0b: weights f32 -> bf16, concat [wq|wk|wv|wo] ----------------
__global__ __launch_bounds__(256) void wconv_k(const float* __restrict__ wq, const float* __restrict__ wk,
                                               const float* __restrict__ wv, const float* __restrict__ wo,
                                               short* __restrict__ dst) {
  const int idx = blockIdx.x * 256 + threadIdx.x;  // 262144 threads, 4 elems each
  const int m = idx >> 16;
  const int base = (idx & 65535) * 4;
  const float* src = (m == 0) ? wq : (m == 1) ? wk : (m == 2) ? wv : wo;
  const f32x4 v = *(const f32x4*)(src + base);
  short4v o;
#pragma unroll
  for (int r = 0; r < 4; ++r) o[r] = f2bf(v[r]);
  *(short4v*)(dst + (size_t)idx * 4) = o;
}

// ---------------- gemm_bt: D[i][j] = sum_k A[i][k]*B[j][k], K=512, tile 128x128, BK=64 ----
// MODE 0: A=Wqk[1024][512], B=XT[4096][512] -> QKB[j*1024+i] bf16 (Q rows i<512 scaled 1/8, +bias(i))
// MODE 1: A=XT[4096][512],  B=Wv[512][512]  -> VB[j*4096+i]  bf16 (+bias(j))
// MODE 2: A=OB[4096][512],  B=Wo[512][512]  -> out f32 (B,512,S) (+bias(j)), i=(b,t)
template <int MODE>
__global__ __launch_bounds__(256) void gemm_bt_k(const short* __restrict__ A, const short* __restrict__ B,
                                                 void* __restrict__ out,
                                                 const float* __restrict__ bias0,
                                                 const float* __restrict__ bias1) {
  constexpr int NI = (MODE == 0) ? 8 : 32;
  __shared__ short As[128 * 64];
  __shared__ short Bs[128 * 64];
  const int bx = blockIdx.x;
  const int it = bx % NI, jt = bx / NI;
  const int tid = threadIdx.x;
  const int lane = tid & 63, wid = tid >> 6;
  const int wi = wid & 1, wj = wid >> 1;
  const int g = lane >> 4, c = lane & 15;

  f32x4 acc[4][4] = {};

  for (int k0 = 0; k0 < 512; k0 += 64) {
    // stage A,B tiles: pre-swizzled global source -> linear LDS; swizzled ds_read below
#pragma unroll
    for (int q = 0; q < 4; ++q) {
      const int blk = wid * 4 + q;              // 16 blocks of 8 rows
      const int row = blk * 8 + (lane >> 3);    // 0..127
      const int ks = ((lane & 7) ^ (row & 7)) * 8;
      gload_lds16(A + (size_t)(it * 128 + row) * 512 + k0 + ks, As + blk * 512);
      gload_lds16(B + (size_t)(jt * 128 + row) * 512 + k0 + ks, Bs + blk * 512);
    }
    __syncthreads();
#pragma unroll
    for (int kk = 0; kk < 2; ++kk) {
      short8 af[4], bfv[4];
#pragma unroll
      for (int mi = 0; mi < 4; ++mi) {
        const int row = wi * 64 + mi * 16 + c;
        af[mi] = *(const short8*)(As + ((row * 64 + kk * 32 + g * 8) ^ ((row & 7) << 3)));
      }
#pragma unroll
      for (int nj = 0; nj < 4; ++nj) {
        const int row = wj * 64 + nj * 16 + c;
        bfv[nj] = *(const short8*)(Bs + ((row * 64 + kk * 32 + g * 8) ^ ((row & 7) << 3)));
      }
#pragma unroll
      for (int mi = 0; mi < 4; ++mi)
#pragma unroll
        for (int nj = 0; nj < 4; ++nj)
          acc[mi][nj] = __builtin_amdgcn_mfma_f32_16x16x32_bf16(af[mi], bfv[nj], acc[mi][nj], 0, 0, 0);
    }
    __syncthreads();
  }

  // epilogue: D[i][j], lane holds rows i0+g*4+r at col j (4 consecutive i -> vector store)
  if constexpr (MODE == 0) {
    short* ob = (short*)out;
    const float scale = (it < 4) ? 0.125f : 1.0f;  // fold 1/sqrt(hd)=1/8 into Q
#pragma unroll
    for (int mi = 0; mi < 4; ++mi) {
      const int i0 = it * 128 + wi * 64 + mi * 16 + g * 4;
      float b4[4];
#pragma unroll
      for (int r = 0; r < 4; ++r) b4[r] = (it < 4) ? bias0[i0 + r] : bias1[i0 + r - 512];
#pragma unroll
      for (int nj = 0; nj < 4; ++nj) {
        const int j = jt * 128 + wj * 64 + nj * 16 + c;
        short4v st;
#pragma unroll
        for (int r = 0; r < 4; ++r) st[r] = f2bf((acc[mi][nj][r] + b4[r]) * scale);
        *(short4v*)(ob + (size_t)j * 1024 + i0) = st;
      }
    }
  } else if constexpr (MODE == 1) {
    short* ob = (short*)out;
#pragma unroll
    for (int mi = 0; mi < 4; ++mi) {
      const int i0 = it * 128 + wi * 64 + mi * 16 + g * 4;
#pragma unroll
      for (int nj = 0; nj < 4; ++nj) {
        const int j = jt * 128 + wj * 64 + nj * 16 + c;
        const float bj = bias0[j];
        short4v st;
#pragma unroll
        for (int r = 0; r < 4; ++r) st[r] = f2bf(acc[mi][nj][r] + bj);
        *(short4v*)(ob + (size_t)j * 4096 + i0) = st;
      }
    }
  } else {
    float* ob = (float*)out;
#pragma unroll
    for (int mi = 0; mi < 4; ++mi) {
      const int i0 = it * 128 + wi * 64 + mi * 16 + g * 4;
      const int bb = i0 >> 11, t = i0 & 2047;
#pragma unroll
      for (int nj = 0; nj < 4; ++nj) {
        const int j = jt * 128 + wj * 64 + nj * 16 + c;
        const float bj = bias0[j];
        f32x4 st;
#pragma unroll
        for (int r = 0; r < 4; ++r) st[r] = acc[mi][nj][r] + bj;
        *(f32x4*)(ob + ((size_t)(bb * 512 + j)) * 2048 + t) = st;
      }
    }
  }
}

// ---------------- attention: per (b,h), flash over kv tiles of 64; 4 waves x 32 q-rows ----
// QKB[(b*2048+s)*1024 + chan]: chan<512 = Q (pre-scaled 1/8), else K. VB[(h*64+d)*4096 + b*2048+s].
// O -> OB[(b*2048+t)*512 + h*64+d] bf16.
__global__ __launch_bounds__(256) void attn_k(const short* __restrict__ qk, const short* __restrict__ v,
                                              short* __restrict__ o) {
  __shared__ short pbuf[4][32 * 64];  // wave-private P / O staging (XOR-swizzled)
  const int qt = blockIdx.x;          // 16 q-tiles
  const int bh = blockIdx.y;          // 16 (b,h)
  const int b = bh >> 3, h = bh & 7;
  const int lane = threadIdx.x & 63, wid = threadIdx.x >> 6;
  const int g = lane >> 4, c = lane & 15;
  const int q0 = qt * 128 + wid * 32;
  short* pl = pbuf[wid];

  const short* qp = qk + (size_t)(b * 2048 + q0) * 1024 + h * 64;
  const short* kp = qk + (size_t)(b * 2048) * 1024 + 512 + h * 64;
  const short* vp = v + (size_t)(h * 64) * 4096 + b * 2048;

  short8 qf[2][2];
#pragma unroll
  for (int mi = 0; mi < 2; ++mi)
#pragma unroll
    for (int kk = 0; kk < 2; ++kk)
      qf[mi][kk] = *(const short8*)(qp + (size_t)(mi * 16 + c) * 1024 + kk * 32 + g * 8);

  f32x4 oacc[2][4] = {};
  float m2[2][4], lsum[2][4];
#pragma unroll
  for (int mi = 0; mi < 2; ++mi)
#pragma unroll
    for (int r = 0; r < 4; ++r) { m2[mi][r] = -1e30f; lsum[mi][r] = 0.f; }

  const float LOG2E = 1.44269504088896f;

  for (int kv0 = 0; kv0 < 2048; kv0 += 64) {
    f32x4 s[2][4] = {};
#pragma unroll
    for (int kk = 0; kk < 2; ++kk) {
      short8 kf[4];
#pragma unroll
      for (int nj = 0; nj < 4; ++nj)
        kf[nj] = *(const short8*)(kp + (size_t)(kv0 + nj * 16 + c) * 1024 + kk * 32 + g * 8);
#pragma unroll
      for (int mi = 0; mi < 2; ++mi)
#pragma unroll
        for (int nj = 0; nj < 4; ++nj)
          s[mi][nj] = __builtin_amdgcn_mfma_f32_16x16x32_bf16(qf[mi][kk], kf[nj], s[mi][nj], 0, 0, 0);
    }
    // V loads issued early: latency hides under softmax VALU
    short8 vf[2][4];
#pragma unroll
    for (int kk = 0; kk < 2; ++kk)
#pragma unroll
      for (int dj = 0; dj < 4; ++dj)
        vf[kk][dj] = *(const short8*)(vp + (size_t)(dj * 16 + c) * 4096 + kv0 + kk * 32 + g * 8);

#pragma unroll
    for (int mi = 0; mi < 2; ++mi) {
      float pm[4];
#pragma unroll
      for (int r = 0; r < 4; ++r)
        pm[r] = fmaxf(fmaxf(s[mi][0][r], s[mi][1][r]), fmaxf(s[mi][2][r], s[mi][3][r])) * LOG2E;
#pragma unroll
      for (int off = 1; off < 16; off <<= 1)
#pragma unroll
        for (int r = 0; r < 4; ++r)
          pm[r] = fmaxf(pm[r], __shfl_xor(pm[r], off));
      float sc[4], rs[4], p[4][4];
#pragma unroll
      for (int r = 0; r < 4; ++r) {
        const float mnew = fmaxf(m2[mi][r], pm[r]);
        sc[r] = __builtin_amdgcn_exp2f(m2[mi][r] - mnew);
        m2[mi][r] = mnew;
      }
#pragma unroll
      for (int nj = 0; nj < 4; ++nj)
#pragma unroll
        for (int r = 0; r < 4; ++r)
          p[nj][r] = __builtin_amdgcn_exp2f(s[mi][nj][r] * LOG2E - m2[mi][r]);
#pragma unroll
      for (int r = 0; r < 4; ++r) rs[r] = (p[0][r] + p[1][r]) + (p[2][r] + p[3][r]);
#pragma unroll
      for (int off = 1; off < 16; off <<= 1)
#pragma unroll
        for (int r = 0; r < 4; ++r) rs[r] += __shfl_xor(rs[r], off);
#pragma unroll
      for (int r = 0; r < 4; ++r) lsum[mi][r] = lsum[mi][r] * sc[r] + rs[r];
#pragma unroll
      for (int dj = 0; dj < 4; ++dj)
#pragma unroll
        for (int r = 0; r < 4; ++r) oacc[mi][dj][r] *= sc[r];
      // P -> bf16 -> swizzled LDS (D-frag -> A-frag transpose), wave-private: no barrier
#pragma unroll
      for (int nj = 0; nj < 4; ++nj)
#pragma unroll
        for (int r = 0; r < 4; ++r) {
          const int t = mi * 16 + g * 4 + r;
          pl[(t * 64 + nj * 16 + c) ^ ((t & 7) << 3)] = f2bf(p[nj][r]);
        }
    }
    // PV
#pragma unroll
    for (int kk = 0; kk < 2; ++kk)
#pragma unroll
      for (int mi = 0; mi < 2; ++mi) {
        const int t = mi * 16 + c;
        const short8 pf = *(const short8*)(pl + ((t * 64 + kk * 32 + g * 8) ^ ((t & 7) << 3)));
#pragma unroll
        for (int dj = 0; dj < 4; ++dj)
          oacc[mi][dj] = __builtin_amdgcn_mfma_f32_16x16x32_bf16(pf, vf[kk][dj], oacc[mi][dj], 0, 0, 0);
      }
  }

  // epilogue: O/l -> bf16 -> LDS transpose -> 16B coalesced stores to OB[t][chan]
#pragma unroll
  for (int mi = 0; mi < 2; ++mi) {
    float rdiv[4];
#pragma unroll
    for (int r = 0; r < 4; ++r) rdiv[r] = 1.f / lsum[mi][r];
#pragma unroll
    for (int dj = 0; dj < 4; ++dj)
#pragma unroll
      for (int r = 0; r < 4; ++r) {
        const int t = mi * 16 + g * 4 + r;
        pl[(t * 64 + dj * 16 + c) ^ ((t & 7) << 3)] = f2bf(oacc[mi][dj][r] * rdiv[r]);
      }
  }
  const int tt = lane >> 1;
#pragma unroll
  for (int pass = 0; pass < 4; ++pass) {
    const int seg = (lane & 1) + pass * 2;
    const short8 w = *(const short8*)(pl + ((tt * 64 + seg * 8) ^ ((tt & 7) << 3)));
    *(short8*)(o + (size_t)(b * 2048 + q0 + tt) * 512 + h * 64 + seg * 8) = w;
  }
}

// ---------------- launcher ----------------
extern "C" void kernel_launch(void* const* d_in, const int* in_sizes, int n_in,
                              void* d_out, int out_size, void* d_ws, size_t ws_size,
                              hipStream_t stream) {
  const float* x  = (const float*)d_in[0];
  const float* wq = (const float*)d_in[1];
  const float* bq = (const float*)d_in[2];
  const float* wk = (const float*)d_in[3];
  const float* bk = (const float*)d_in[4];
  const float* wv = (const float*)d_in[5];
  const float* bv = (const float*)d_in[6];
  const float* wo = (const float*)d_in[7];
  const float* bo = (const float*)d_in[8];

  short* XT  = (short*)d_ws;                       // 4096*512 bf16
  short* WQK = XT + (size_t)4096 * 512;            // 1024*512 (wq|wk), then wv, wo contiguous
  short* WV  = WQK + (size_t)1024 * 512;
  short* WO  = WV + (size_t)512 * 512;
  short* QKB = WO + (size_t)512 * 512;             // 4096*1024
  short* VB  = QKB + (size_t)4096 * 1024;          // 512*4096
  short* OB  = VB + (size_t)512 * 4096;            // 4096*512

  xpose_k<<<dim3(64, 16, 2), 256, 0, stream>>>(x, XT);
  wconv_k<<<dim3(1024), 256, 0, stream>>>(wq, wk, wv, wo, WQK);
  gemm_bt_k<0><<<dim3(256), 256, 0, stream>>>(WQK, XT, (void*)QKB, bq, bk);
  gemm_bt_k<1><<<dim3(128), 256, 0, stream>>>(XT, WV, (void*)VB, bv, nullptr);
  attn_k<<<dim3(16, 16), 256, 0, stream>>>(QKB, VB, OB);
  gemm_bt_k<2><<<dim3(128), 256, 0, stream>>>(OB, WO, d_out, bo, nullptr);
}

// Round 2
// 136.740 us; speedup vs baseline: 1.0898x; 1.0898x over previous
//
#include <hip/hip_runtime.h>
#include <hip/hip_bf16.h>

// MHSA: x(2,512,2048) f32, 8 heads x 64. All heavy math in bf16 MFMA 16x16x32.
// Pipeline: xpose -> wconv -> gemm_bt<0>(QK) -> gemm_bt<1>(V) -> attn(kv-split 4) -> merge -> gemm_bt<2>(out)

typedef __attribute__((ext_vector_type(8))) short short8;   // 8 bf16 = 4 VGPR (MFMA A/B frag)
typedef __attribute__((ext_vector_type(4))) short short4v;  // 4 bf16 (8B store)
typedef __attribute__((ext_vector_type(4))) float f32x4;    // MFMA C/D frag

#define DEV static __device__ __forceinline__

DEV short f2bf(float f) {  // fp32 -> bf16 RNE
  union { float f; unsigned u; } v; v.f = f;
  unsigned r = (v.u + 0x7FFFu + ((v.u >> 16) & 1u)) >> 16;
  return (short)r;
}

DEV void gload_lds16(const void* g, void* l) {
  // wave-uniform LDS base; HW writes lane*16B
  __builtin_amdgcn_global_load_lds((const __attribute__((address_space(1))) void*)g,
                                   (__attribute__((address_space(3))) void*)l, 16, 0, 0);
}

// ---------------- pass 0a: x (B,512,2048) f32 -> XT[(b*2048+s)][512] bf16 ----------------
__global__ __launch_bounds__(256) void xpose_k(const float* __restrict__ x, short* __restrict__ xt) {
  __shared__ float tile[32][33];
  const int b = blockIdx.z;
  const int s0 = blockIdx.x * 32, c0 = blockIdx.y * 32;
  const int tl = threadIdx.x & 31, tr = threadIdx.x >> 5;  // tr 0..7
  const float* src = x + ((size_t)b * 512 + c0) * 2048 + s0;
#pragma unroll
  for (int i = 0; i < 4; ++i)
    tile[tr + i * 8][tl] = src[(size_t)(tr + i * 8) * 2048 + tl];  // tile[c][s]
  __syncthreads();
  short* dst = xt + ((size_t)b * 2048 + s0) * 512 + c0;
#pragma unroll
  for (int i = 0; i < 4; ++i) {
    const int s = tr + i * 8;
    dst[(size_t)s * 512 + tl] = f2bf(tile[tl][s]);
  }
}

// ---------------- pass 0b: weights f32 -> bf16, concat [wq|wk|wv|wo] ----------------
__global__ __launch_bounds__(256) void wconv_k(const float* __restrict__ wq, const float* __restrict__ wk,
                                               const float* __restrict__ wv, const float* __restrict__ wo,
                                               short* __restrict__ dst) {
  const int idx = blockIdx.x * 256 + threadIdx.x;  // 262144 threads, 4 elems each
  const int m = idx >> 16;
  const int base = (idx & 65535) * 4;
  const float* src = (m == 0) ? wq : (m == 1) ? wk : (m == 2) ? wv : wo;
  const f32x4 v = *(const f32x4*)(src + base);
  short4v o;
#pragma unroll
  for (int r = 0; r < 4; ++r) o[r] = f2bf(v[r]);
  *(short4v*)(dst + (size_t)idx * 4) = o;
}

// ---------------- gemm_bt: D[i][j] = sum_k A[i][k]*B[j][k], K=512, tile 128x128, BK=64 ----
// MODE 0: A=Wqk[1024][512], B=XT[4096][512] -> QKB[j*1024+i] bf16 (Q rows i<512 scaled 1/8, +bias(i))
// MODE 1: A=XT[4096][512],  B=Wv[512][512]  -> VB[j*4096+i]  bf16 (+bias(j))
// MODE 2: A=OB[4096][512],  B=Wo[512][512]  -> out f32 (B,512,S) (+bias(j)), i=(b,t)
template <int MODE>
__global__ __launch_bounds__(256) void gemm_bt_k(const short* __restrict__ A, const short* __restrict__ B,
                                                 void* __restrict__ out,
                                                 const float* __restrict__ bias0,
                                                 const float* __restrict__ bias1) {
  constexpr int NI = (MODE == 0) ? 8 : 32;
  __shared__ short As[128 * 64];
  __shared__ short Bs[128 * 64];
  const int bx = blockIdx.x;
  const int it = bx % NI, jt = bx / NI;
  const int tid = threadIdx.x;
  const int lane = tid & 63, wid = tid >> 6;
  const int wi = wid & 1, wj = wid >> 1;
  const int g = lane >> 4, c = lane & 15;

  f32x4 acc[4][4] = {};

  for (int k0 = 0; k0 < 512; k0 += 64) {
    // stage A,B tiles: pre-swizzled global source -> linear LDS; swizzled ds_read below
#pragma unroll
    for (int q = 0; q < 4; ++q) {
      const int blk = wid * 4 + q;              // 16 blocks of 8 rows
      const int row = blk * 8 + (lane >> 3);    // 0..127
      const int ks = ((lane & 7) ^ (row & 7)) * 8;
      gload_lds16(A + (size_t)(it * 128 + row) * 512 + k0 + ks, As + blk * 512);
      gload_lds16(B + (size_t)(jt * 128 + row) * 512 + k0 + ks, Bs + blk * 512);
    }
    __syncthreads();
#pragma unroll
    for (int kk = 0; kk < 2; ++kk) {
      short8 af[4], bfv[4];
#pragma unroll
      for (int mi = 0; mi < 4; ++mi) {
        const int row = wi * 64 + mi * 16 + c;
        af[mi] = *(const short8*)(As + ((row * 64 + kk * 32 + g * 8) ^ ((row & 7) << 3)));
      }
#pragma unroll
      for (int nj = 0; nj < 4; ++nj) {
        const int row = wj * 64 + nj * 16 + c;
        bfv[nj] = *(const short8*)(Bs + ((row * 64 + kk * 32 + g * 8) ^ ((row & 7) << 3)));
      }
#pragma unroll
      for (int mi = 0; mi < 4; ++mi)
#pragma unroll
        for (int nj = 0; nj < 4; ++nj)
          acc[mi][nj] = __builtin_amdgcn_mfma_f32_16x16x32_bf16(af[mi], bfv[nj], acc[mi][nj], 0, 0, 0);
    }
    __syncthreads();
  }

  // epilogue: D[i][j], lane holds rows i0+g*4+r at col j (4 consecutive i -> vector store)
  if constexpr (MODE == 0) {
    short* ob = (short*)out;
    const float scale = (it < 4) ? 0.125f : 1.0f;  // fold 1/sqrt(hd)=1/8 into Q
#pragma unroll
    for (int mi = 0; mi < 4; ++mi) {
      const int i0 = it * 128 + wi * 64 + mi * 16 + g * 4;
      float b4[4];
#pragma unroll
      for (int r = 0; r < 4; ++r) b4[r] = (it < 4) ? bias0[i0 + r] : bias1[i0 + r - 512];
#pragma unroll
      for (int nj = 0; nj < 4; ++nj) {
        const int j = jt * 128 + wj * 64 + nj * 16 + c;
        short4v st;
#pragma unroll
        for (int r = 0; r < 4; ++r) st[r] = f2bf((acc[mi][nj][r] + b4[r]) * scale);
        *(short4v*)(ob + (size_t)j * 1024 + i0) = st;
      }
    }
  } else if constexpr (MODE == 1) {
    short* ob = (short*)out;
#pragma unroll
    for (int mi = 0; mi < 4; ++mi) {
      const int i0 = it * 128 + wi * 64 + mi * 16 + g * 4;
#pragma unroll
      for (int nj = 0; nj < 4; ++nj) {
        const int j = jt * 128 + wj * 64 + nj * 16 + c;
        const float bj = bias0[j];
        short4v st;
#pragma unroll
        for (int r = 0; r < 4; ++r) st[r] = f2bf(acc[mi][nj][r] + bj);
        *(short4v*)(ob + (size_t)j * 4096 + i0) = st;
      }
    }
  } else {
    float* ob = (float*)out;
#pragma unroll
    for (int mi = 0; mi < 4; ++mi) {
      const int i0 = it * 128 + wi * 64 + mi * 16 + g * 4;
      const int bb = i0 >> 11, t = i0 & 2047;
#pragma unroll
      for (int nj = 0; nj < 4; ++nj) {
        const int j = jt * 128 + wj * 64 + nj * 16 + c;
        const float bj = bias0[j];
        f32x4 st;
#pragma unroll
        for (int r = 0; r < 4; ++r) st[r] = acc[mi][nj][r] + bj;
        *(f32x4*)(ob + ((size_t)(bb * 512 + j)) * 2048 + t) = st;
      }
    }
  }
}

// ---------------- attention (kv-split): per (b,h,seg), flash over 8 kv tiles of 64 ----
// QKB[(b*2048+s)*1024 + chan]: chan<512 = Q (pre-scaled 1/8), else K. VB[(h*64+d)*4096 + b*2048+s].
// Partials: OP[(seg*32768 + bh*2048 + row)*64 + d] f32 (unnormalized), Mb/Lb[seg*32768 + bh*2048 + row].
__global__ __launch_bounds__(256) void attn_k(const short* __restrict__ qk, const short* __restrict__ v,
                                              float* __restrict__ OP, float* __restrict__ Mb,
                                              float* __restrict__ Lb) {
  __shared__ short pbuf[4][32 * 64];  // wave-private P staging (XOR-swizzled)
  const int qt = blockIdx.x;          // 16 q-tiles
  const int bh = blockIdx.y;          // 16 (b,h)
  const int seg = blockIdx.z;         // 4 kv segments of 512
  const int b = bh >> 3, h = bh & 7;
  const int lane = threadIdx.x & 63, wid = threadIdx.x >> 6;
  const int g = lane >> 4, c = lane & 15;
  const int q0 = qt * 128 + wid * 32;
  short* pl = pbuf[wid];

  const short* qp = qk + (size_t)(b * 2048 + q0) * 1024 + h * 64;
  const short* kp = qk + (size_t)(b * 2048) * 1024 + 512 + h * 64;
  const short* vp = v + (size_t)(h * 64) * 4096 + b * 2048;

  short8 qf[2][2];
#pragma unroll
  for (int mi = 0; mi < 2; ++mi)
#pragma unroll
    for (int kk = 0; kk < 2; ++kk)
      qf[mi][kk] = *(const short8*)(qp + (size_t)(mi * 16 + c) * 1024 + kk * 32 + g * 8);

  f32x4 oacc[2][4] = {};
  float m2[2][4], lsum[2][4];
#pragma unroll
  for (int mi = 0; mi < 2; ++mi)
#pragma unroll
    for (int r = 0; r < 4; ++r) { m2[mi][r] = -1e30f; lsum[mi][r] = 0.f; }

  const float LOG2E = 1.44269504088896f;

  for (int kv0 = seg * 512; kv0 < seg * 512 + 512; kv0 += 64) {
    f32x4 s[2][4] = {};
#pragma unroll
    for (int kk = 0; kk < 2; ++kk) {
      short8 kf[4];
#pragma unroll
      for (int nj = 0; nj < 4; ++nj)
        kf[nj] = *(const short8*)(kp + (size_t)(kv0 + nj * 16 + c) * 1024 + kk * 32 + g * 8);
#pragma unroll
      for (int mi = 0; mi < 2; ++mi)
#pragma unroll
        for (int nj = 0; nj < 4; ++nj)
          s[mi][nj] = __builtin_amdgcn_mfma_f32_16x16x32_bf16(qf[mi][kk], kf[nj], s[mi][nj], 0, 0, 0);
    }
    // V loads issued early: latency hides under softmax VALU
    short8 vf[2][4];
#pragma unroll
    for (int kk = 0; kk < 2; ++kk)
#pragma unroll
      for (int dj = 0; dj < 4; ++dj)
        vf[kk][dj] = *(const short8*)(vp + (size_t)(dj * 16 + c) * 4096 + kv0 + kk * 32 + g * 8);

#pragma unroll
    for (int mi = 0; mi < 2; ++mi) {
      float pm[4];
#pragma unroll
      for (int r = 0; r < 4; ++r)
        pm[r] = fmaxf(fmaxf(s[mi][0][r], s[mi][1][r]), fmaxf(s[mi][2][r], s[mi][3][r])) * LOG2E;
#pragma unroll
      for (int off = 1; off < 16; off <<= 1)
#pragma unroll
        for (int r = 0; r < 4; ++r)
          pm[r] = fmaxf(pm[r], __shfl_xor(pm[r], off));
      float sc[4], rs[4], p[4][4];
#pragma unroll
      for (int r = 0; r < 4; ++r) {
        const float mnew = fmaxf(m2[mi][r], pm[r]);
        sc[r] = __builtin_amdgcn_exp2f(m2[mi][r] - mnew);
        m2[mi][r] = mnew;
      }
#pragma unroll
      for (int nj = 0; nj < 4; ++nj)
#pragma unroll
        for (int r = 0; r < 4; ++r)
          p[nj][r] = __builtin_amdgcn_exp2f(s[mi][nj][r] * LOG2E - m2[mi][r]);
#pragma unroll
      for (int r = 0; r < 4; ++r) rs[r] = (p[0][r] + p[1][r]) + (p[2][r] + p[3][r]);
#pragma unroll
      for (int off = 1; off < 16; off <<= 1)
#pragma unroll
        for (int r = 0; r < 4; ++r) rs[r] += __shfl_xor(rs[r], off);
#pragma unroll
      for (int r = 0; r < 4; ++r) lsum[mi][r] = lsum[mi][r] * sc[r] + rs[r];
#pragma unroll
      for (int dj = 0; dj < 4; ++dj)
#pragma unroll
        for (int r = 0; r < 4; ++r) oacc[mi][dj][r] *= sc[r];
      // P -> bf16 -> swizzled LDS (D-frag -> A-frag transpose), wave-private: no barrier
#pragma unroll
      for (int nj = 0; nj < 4; ++nj)
#pragma unroll
        for (int r = 0; r < 4; ++r) {
          const int t = mi * 16 + g * 4 + r;
          pl[(t * 64 + nj * 16 + c) ^ ((t & 7) << 3)] = f2bf(p[nj][r]);
        }
    }
    // PV
#pragma unroll
    for (int kk = 0; kk < 2; ++kk)
#pragma unroll
      for (int mi = 0; mi < 2; ++mi) {
        const int t = mi * 16 + c;
        const short8 pf = *(const short8*)(pl + ((t * 64 + kk * 32 + g * 8) ^ ((t & 7) << 3)));
#pragma unroll
        for (int dj = 0; dj < 4; ++dj)
          oacc[mi][dj] = __builtin_amdgcn_mfma_f32_16x16x32_bf16(pf, vf[kk][dj], oacc[mi][dj], 0, 0, 0);
      }
  }

  // epilogue: write unnormalized partial O (f32) + m,l per row
  const size_t rbase = (size_t)seg * 32768 + (size_t)bh * 2048 + q0;
#pragma unroll
  for (int mi = 0; mi < 2; ++mi) {
#pragma unroll
    for (int dj = 0; dj < 4; ++dj)
#pragma unroll
      for (int r = 0; r < 4; ++r) {
        const int t = mi * 16 + g * 4 + r;
        OP[(rbase + t) * 64 + dj * 16 + c] = oacc[mi][dj][r];
      }
    if (c == 0) {
#pragma unroll
      for (int r = 0; r < 4; ++r) {
        const int t = mi * 16 + g * 4 + r;
        Mb[rbase + t] = m2[mi][r];
        Lb[rbase + t] = lsum[mi][r];
      }
    }
  }
}

// ---------------- merge: combine 4 kv-segment partials -> OB bf16 [(b*2048+t)*512 + h*64+d] ----
__global__ __launch_bounds__(256) void merge_k(const float* __restrict__ OP, const float* __restrict__ Mb,
                                               const float* __restrict__ Lb, short* __restrict__ o) {
  const int gid = blockIdx.x * 256 + threadIdx.x;  // 131072 threads
  const int row = gid >> 2;                        // bh*2048 + s
  const int dg = (gid & 3) * 16;
  float m[4], l[4];
#pragma unroll
  for (int s = 0; s < 4; ++s) { m[s] = Mb[s * 32768 + row]; l[s] = Lb[s * 32768 + row]; }
  float M = fmaxf(fmaxf(m[0], m[1]), fmaxf(m[2], m[3]));
  float w[4], L = 0.f;
#pragma unroll
  for (int s = 0; s < 4; ++s) { w[s] = __builtin_amdgcn_exp2f(m[s] - M); L += l[s] * w[s]; }
  const float rinv = 1.f / L;
  float acc[16];
#pragma unroll
  for (int j = 0; j < 16; ++j) acc[j] = 0.f;
#pragma unroll
  for (int s = 0; s < 4; ++s) {
#pragma unroll
    for (int q = 0; q < 4; ++q) {
      const f32x4 vv = *(const f32x4*)(OP + ((size_t)s * 32768 + row) * 64 + dg + q * 4);
#pragma unroll
      for (int r = 0; r < 4; ++r) acc[q * 4 + r] += vv[r] * w[s];
    }
  }
  const int bh = row >> 11, srow = row & 2047;
  const int b = bh >> 3, h = bh & 7;
  short8 st[2];
#pragma unroll
  for (int j = 0; j < 16; ++j) st[j >> 3][j & 7] = f2bf(acc[j] * rinv);
  short* dst = o + (size_t)(b * 2048 + srow) * 512 + h * 64 + dg;
  *(short8*)dst = st[0];
  *(short8*)(dst + 8) = st[1];
}

// ---------------- launcher ----------------
extern "C" void kernel_launch(void* const* d_in, const int* in_sizes, int n_in,
                              void* d_out, int out_size, void* d_ws, size_t ws_size,
                              hipStream_t stream) {
  const float* x  = (const float*)d_in[0];
  const float* wq = (const float*)d_in[1];
  const float* bq = (const float*)d_in[2];
  const float* wk = (const float*)d_in[3];
  const float* bk = (const float*)d_in[4];
  const float* wv = (const float*)d_in[5];
  const float* bv = (const float*)d_in[6];
  const float* wo = (const float*)d_in[7];
  const float* bo = (const float*)d_in[8];

  short* XT  = (short*)d_ws;                       // 4096*512 bf16
  short* WQK = XT + (size_t)4096 * 512;            // 1024*512 (wq|wk), then wv, wo contiguous
  short* WV  = WQK + (size_t)1024 * 512;
  short* WO  = WV + (size_t)512 * 512;
  short* QKB = WO + (size_t)512 * 512;             // 4096*1024
  short* VB  = QKB + (size_t)4096 * 1024;          // 512*4096
  short* OB  = VB + (size_t)512 * 4096;            // 4096*512
  float* OP  = (float*)(OB + (size_t)4096 * 512);  // 4*32768*64 f32 partial O
  float* Mb  = OP + (size_t)4 * 32768 * 64;        // 4*32768 f32
  float* Lb  = Mb + (size_t)4 * 32768;             // 4*32768 f32

  xpose_k<<<dim3(64, 16, 2), 256, 0, stream>>>(x, XT);
  wconv_k<<<dim3(1024), 256, 0, stream>>>(wq, wk, wv, wo, WQK);
  gemm_bt_k<0><<<dim3(256), 256, 0, stream>>>(WQK, XT, (void*)QKB, bq, bk);
  gemm_bt_k<1><<<dim3(128), 256, 0, stream>>>(XT, WV, (void*)VB, bv, nullptr);
  attn_k<<<dim3(16, 16, 4), 256, 0, stream>>>(QKB, VB, OP, Mb, Lb);
  merge_k<<<dim3(512), 256, 0, stream>>>(OP, Mb, Lb, OB);
  gemm_bt_k<2><<<dim3(128), 256, 0, stream>>>(OB, WO, d_out, bo, nullptr);
}

// Round 4
// 105.610 us; speedup vs baseline: 1.4110x; 1.2948x over previous
//
#include <hip/hip_runtime.h>
#include <hip/hip_bf16.h>

// MHSA: x(2,512,2048) f32, 8 heads x 64. All heavy math in bf16 MFMA 16x16x32.
// Pipeline: xpose -> wconv -> gemm_bt<0>(QK) -> gemm_bt<1>(V) -> attn(kv-split 4) -> merge -> gemm_bt<2>(out)
// attn: swapped QK^T / swapped PV (col-t layout), K/V LDS double-buffered per block.
// Numerics: P packed via verified f2bf (RNE); LOG2E applied in f32 at softmax (R2-exact path).

typedef __attribute__((ext_vector_type(8))) short short8;   // 8 bf16 = 4 VGPR (MFMA A/B frag)
typedef __attribute__((ext_vector_type(4))) short short4v;  // 4 bf16 (8B store)
typedef __attribute__((ext_vector_type(4))) float f32x4;    // MFMA C/D frag
typedef __attribute__((ext_vector_type(2))) int int2v;      // 8B LDS store

#define DEV static __device__ __forceinline__

DEV short f2bf(float f) {  // fp32 -> bf16 RNE
  union { float f; unsigned u; } v; v.f = f;
  unsigned r = (v.u + 0x7FFFu + ((v.u >> 16) & 1u)) >> 16;
  return (short)r;
}

DEV void gload_lds16(const void* g, void* l) {
  // wave-uniform LDS base; HW writes lane*16B
  __builtin_amdgcn_global_load_lds((const __attribute__((address_space(1))) void*)g,
                                   (__attribute__((address_space(3))) void*)l, 16, 0, 0);
}

// ---------------- pass 0a: x (B,512,2048) f32 -> XT[(b*2048+s)][512] bf16 ----------------
__global__ __launch_bounds__(256) void xpose_k(const float* __restrict__ x, short* __restrict__ xt) {
  __shared__ float tile[32][33];
  const int b = blockIdx.z;
  const int s0 = blockIdx.x * 32, c0 = blockIdx.y * 32;
  const int tl = threadIdx.x & 31, tr = threadIdx.x >> 5;  // tr 0..7
  const float* src = x + ((size_t)b * 512 + c0) * 2048 + s0;
#pragma unroll
  for (int i = 0; i < 4; ++i)
    tile[tr + i * 8][tl] = src[(size_t)(tr + i * 8) * 2048 + tl];  // tile[c][s]
  __syncthreads();
  short* dst = xt + ((size_t)b * 2048 + s0) * 512 + c0;
#pragma unroll
  for (int i = 0; i < 4; ++i) {
    const int s = tr + i * 8;
    dst[(size_t)s * 512 + tl] = f2bf(tile[tl][s]);
  }
}

// ---------------- pass 0b: weights f32 -> bf16, concat [wq|wk|wv|wo] ----------------
__global__ __launch_bounds__(256) void wconv_k(const float* __restrict__ wq, const float* __restrict__ wk,
                                               const float* __restrict__ wv, const float* __restrict__ wo,
                                               short* __restrict__ dst) {
  const int idx = blockIdx.x * 256 + threadIdx.x;  // 262144 threads, 4 elems each
  const int m = idx >> 16;
  const int base = (idx & 65535) * 4;
  const float* src = (m == 0) ? wq : (m == 1) ? wk : (m == 2) ? wv : wo;
  const f32x4 v = *(const f32x4*)(src + base);
  short4v o;
#pragma unroll
  for (int r = 0; r < 4; ++r) o[r] = f2bf(v[r]);
  *(short4v*)(dst + (size_t)idx * 4) = o;
}

// ---------------- gemm_bt: D[i][j] = sum_k A[i][k]*B[j][k], K=512, tile 128x128, BK=64 ----
// MODE 0: A=Wqk[1024][512], B=XT[4096][512] -> QKB[j*1024+i] bf16 (Q rows i<512 scaled 1/8, +bias(i))
// MODE 1: A=XT[4096][512],  B=Wv[512][512]  -> VB[j*4096+i]  bf16 (+bias(j))
// MODE 2: A=OB[4096][512],  B=Wo[512][512]  -> out f32 (B,512,S) (+bias(j)), i=(b,t)
template <int MODE>
__global__ __launch_bounds__(256) void gemm_bt_k(const short* __restrict__ A, const short* __restrict__ B,
                                                 void* __restrict__ out,
                                                 const float* __restrict__ bias0,
                                                 const float* __restrict__ bias1) {
  constexpr int NI = (MODE == 0) ? 8 : 32;
  __shared__ short As[128 * 64];
  __shared__ short Bs[128 * 64];
  const int bx = blockIdx.x;
  const int it = bx % NI, jt = bx / NI;
  const int tid = threadIdx.x;
  const int lane = tid & 63, wid = tid >> 6;
  const int wi = wid & 1, wj = wid >> 1;
  const int g = lane >> 4, c = lane & 15;

  f32x4 acc[4][4] = {};

  for (int k0 = 0; k0 < 512; k0 += 64) {
    // stage A,B tiles: pre-swizzled global source -> linear LDS; swizzled ds_read below
#pragma unroll
    for (int q = 0; q < 4; ++q) {
      const int blk = wid * 4 + q;              // 16 blocks of 8 rows
      const int row = blk * 8 + (lane >> 3);    // 0..127
      const int ks = ((lane & 7) ^ (row & 7)) * 8;
      gload_lds16(A + (size_t)(it * 128 + row) * 512 + k0 + ks, As + blk * 512);
      gload_lds16(B + (size_t)(jt * 128 + row) * 512 + k0 + ks, Bs + blk * 512);
    }
    __syncthreads();
#pragma unroll
    for (int kk = 0; kk < 2; ++kk) {
      short8 af[4], bfv[4];
#pragma unroll
      for (int mi = 0; mi < 4; ++mi) {
        const int row = wi * 64 + mi * 16 + c;
        af[mi] = *(const short8*)(As + ((row * 64 + kk * 32 + g * 8) ^ ((row & 7) << 3)));
      }
#pragma unroll
      for (int nj = 0; nj < 4; ++nj) {
        const int row = wj * 64 + nj * 16 + c;
        bfv[nj] = *(const short8*)(Bs + ((row * 64 + kk * 32 + g * 8) ^ ((row & 7) << 3)));
      }
#pragma unroll
      for (int mi = 0; mi < 4; ++mi)
#pragma unroll
        for (int nj = 0; nj < 4; ++nj)
          acc[mi][nj] = __builtin_amdgcn_mfma_f32_16x16x32_bf16(af[mi], bfv[nj], acc[mi][nj], 0, 0, 0);
    }
    __syncthreads();
  }

  // epilogue: D[i][j], lane holds rows i0+g*4+r at col j (4 consecutive i -> vector store)
  if constexpr (MODE == 0) {
    short* ob = (short*)out;
    const float scale = (it < 4) ? 0.125f : 1.0f;  // fold 1/sqrt(hd)=1/8 into Q (R2-exact)
#pragma unroll
    for (int mi = 0; mi < 4; ++mi) {
      const int i0 = it * 128 + wi * 64 + mi * 16 + g * 4;
      float b4[4];
#pragma unroll
      for (int r = 0; r < 4; ++r) b4[r] = (it < 4) ? bias0[i0 + r] : bias1[i0 + r - 512];
#pragma unroll
      for (int nj = 0; nj < 4; ++nj) {
        const int j = jt * 128 + wj * 64 + nj * 16 + c;
        short4v st;
#pragma unroll
        for (int r = 0; r < 4; ++r) st[r] = f2bf((acc[mi][nj][r] + b4[r]) * scale);
        *(short4v*)(ob + (size_t)j * 1024 + i0) = st;
      }
    }
  } else if constexpr (MODE == 1) {
    short* ob = (short*)out;
#pragma unroll
    for (int mi = 0; mi < 4; ++mi) {
      const int i0 = it * 128 + wi * 64 + mi * 16 + g * 4;
#pragma unroll
      for (int nj = 0; nj < 4; ++nj) {
        const int j = jt * 128 + wj * 64 + nj * 16 + c;
        const float bj = bias0[j];
        short4v st;
#pragma unroll
        for (int r = 0; r < 4; ++r) st[r] = f2bf(acc[mi][nj][r] + bj);
        *(short4v*)(ob + (size_t)j * 4096 + i0) = st;
      }
    }
  } else {
    float* ob = (float*)out;
#pragma unroll
    for (int mi = 0; mi < 4; ++mi) {
      const int i0 = it * 128 + wi * 64 + mi * 16 + g * 4;
      const int bb = i0 >> 11, t = i0 & 2047;
#pragma unroll
      for (int nj = 0; nj < 4; ++nj) {
        const int j = jt * 128 + wj * 64 + nj * 16 + c;
        const float bj = bias0[j];
        f32x4 st;
#pragma unroll
        for (int r = 0; r < 4; ++r) st[r] = acc[mi][nj][r] + bj;
        *(f32x4*)(ob + ((size_t)(bb * 512 + j)) * 2048 + t) = st;
      }
    }
  }
}

// ---------------- attention (kv-split): per (b,h,seg), flash over 8 kv tiles of 64 ----
// QKB[(b*2048+s)*1024 + chan]: chan<512 = Q (pre-scaled 1/8), else K. VB[(h*64+d)*4096 + b*2048+s].
// Swapped layout: QK^T -> S^T (lane col t=nj*16+c), PV -> O^T (lane col t=o*16+c, rows d).
// Partials: OP[(seg*32768 + bh*2048 + row)*64 + d] f32 (unnormalized), Mb/Lb (log2-domain m).
__global__ __launch_bounds__(256) void attn_k(const short* __restrict__ qk, const short* __restrict__ v,
                                              float* __restrict__ OP, float* __restrict__ Mb,
                                              float* __restrict__ Lb) {
  __shared__ short ks[2][64 * 64];    // K tile [s][d], swizzled
  __shared__ short vs[2][64 * 64];    // V tile [d][s], swizzled
  __shared__ short pbuf[4][32 * 64];  // per-wave P [t][s], swizzled
  const int qt = blockIdx.x;          // 16 q-tiles
  const int bh = blockIdx.y;          // 16 (b,h)
  const int seg = blockIdx.z;         // 4 kv segments of 512
  const int b = bh >> 3, h = bh & 7;
  const int lane = threadIdx.x & 63, wid = threadIdx.x >> 6;
  const int g = lane >> 4, c = lane & 15;
  const int q0 = qt * 128 + wid * 32;
  short* pl = pbuf[wid];

  const short* qp = qk + (size_t)(b * 2048 + q0) * 1024 + h * 64;
  const short* kb = qk + (size_t)(b * 2048) * 1024 + 512 + h * 64;
  const short* vb = v + (size_t)(h * 64) * 4096 + b * 2048;

  // Q as B-operand frags (rows t, once per block)
  short8 qf[2][2];
#pragma unroll
  for (int nj = 0; nj < 2; ++nj)
#pragma unroll
    for (int kk = 0; kk < 2; ++kk)
      qf[nj][kk] = *(const short8*)(qp + (size_t)(nj * 16 + c) * 1024 + kk * 32 + g * 8);

  // staging geometry: row-of-8 blocks, XOR-pre-swizzled source column (16B granules)
  const int sr = lane >> 3;                 // 0..7 (== row&7)
  const int scol = ((lane & 7) ^ sr) * 8;   // shorts

  const int kvbeg = seg * 512;
  {
#pragma unroll
    for (int q = 0; q < 2; ++q) {
      const int blk = wid * 2 + q;
      const int row = blk * 8 + sr;
      gload_lds16(kb + (size_t)(kvbeg + row) * 1024 + scol, &ks[0][blk * 512]);
      gload_lds16(vb + (size_t)row * 4096 + kvbeg + scol, &vs[0][blk * 512]);
    }
  }
  __syncthreads();

  f32x4 oacc[4][2] = {};  // [dj][o]: O^T rows d=dj*16+g*4+r, col t=o*16+c
  float mreg[2] = {-1e30f, -1e30f}, lreg[2] = {0.f, 0.f};

  const float LOG2E = 1.44269504088896f;

  for (int it8 = 0; it8 < 8; ++it8) {
    const int bufi = it8 & 1;
    if (it8 < 7) {
      const int kv0 = kvbeg + (it8 + 1) * 64;
#pragma unroll
      for (int q = 0; q < 2; ++q) {
        const int blk = wid * 2 + q;
        const int row = blk * 8 + sr;
        gload_lds16(kb + (size_t)(kv0 + row) * 1024 + scol, &ks[bufi ^ 1][blk * 512]);
        gload_lds16(vb + (size_t)row * 4096 + kv0 + scol, &vs[bufi ^ 1][blk * 512]);
      }
    }

    // QK^T swapped: S^T[mi][nj], rows s=mi*16+g*4+r, col t=nj*16+c
    f32x4 st[4][2] = {};
#pragma unroll
    for (int kk = 0; kk < 2; ++kk) {
      short8 kf[4];
#pragma unroll
      for (int mi = 0; mi < 4; ++mi) {
        const int row = mi * 16 + c;
        kf[mi] = *(const short8*)(&ks[bufi][(row * 64 + kk * 32 + g * 8) ^ ((row & 7) << 3)]);
      }
#pragma unroll
      for (int mi = 0; mi < 4; ++mi)
#pragma unroll
        for (int nj = 0; nj < 2; ++nj)
          st[mi][nj] = __builtin_amdgcn_mfma_f32_16x16x32_bf16(kf[mi], qf[nj][kk], st[mi][nj], 0, 0, 0);
    }

    // row(t) max: lane-local 16 + 2 shuffle rounds across g-groups; scale to log2-domain
    float pm[2];
#pragma unroll
    for (int nj = 0; nj < 2; ++nj) {
      float a = fmaxf(fmaxf(st[0][nj][0], st[0][nj][1]), fmaxf(st[0][nj][2], st[0][nj][3]));
#pragma unroll
      for (int mi = 1; mi < 4; ++mi)
        a = fmaxf(a, fmaxf(fmaxf(st[mi][nj][0], st[mi][nj][1]), fmaxf(st[mi][nj][2], st[mi][nj][3])));
      a = fmaxf(a, __shfl_xor(a, 16));
      a = fmaxf(a, __shfl_xor(a, 32));
      pm[nj] = a * LOG2E;
    }
    // exact defer: if no row grows its max, sc==1 -> skip rescale entirely
    if (!__all(pm[0] <= mreg[0] && pm[1] <= mreg[1])) {
#pragma unroll
      for (int nj = 0; nj < 2; ++nj) {
        const float mnew = fmaxf(mreg[nj], pm[nj]);
        const float scf = __builtin_amdgcn_exp2f(mreg[nj] - mnew);
        mreg[nj] = mnew;
        lreg[nj] *= scf;
#pragma unroll
        for (int dj = 0; dj < 4; ++dj)
#pragma unroll
          for (int r = 0; r < 4; ++r) oacc[dj][nj][r] *= scf;
      }
    }

    // P = exp2(S*LOG2E - m), pack bf16 via f2bf (RNE), swizzled 8B stores to pbuf[t][s]
    float rs[2] = {0.f, 0.f};
#pragma unroll
    for (int mi = 0; mi < 4; ++mi)
#pragma unroll
      for (int nj = 0; nj < 2; ++nj) {
        const float p0 = __builtin_amdgcn_exp2f(st[mi][nj][0] * LOG2E - mreg[nj]);
        const float p1 = __builtin_amdgcn_exp2f(st[mi][nj][1] * LOG2E - mreg[nj]);
        const float p2 = __builtin_amdgcn_exp2f(st[mi][nj][2] * LOG2E - mreg[nj]);
        const float p3 = __builtin_amdgcn_exp2f(st[mi][nj][3] * LOG2E - mreg[nj]);
        rs[nj] += (p0 + p1) + (p2 + p3);
        const unsigned w0 = (unsigned short)f2bf(p0) | ((unsigned)(unsigned short)f2bf(p1) << 16);
        const unsigned w1 = (unsigned short)f2bf(p2) | ((unsigned)(unsigned short)f2bf(p3) << 16);
        const int t = nj * 16 + c;
        *(int2v*)(pl + ((t * 64 + mi * 16 + g * 4) ^ ((t & 7) << 3))) = (int2v){(int)w0, (int)w1};
      }
#pragma unroll
    for (int nj = 0; nj < 2; ++nj) {
      rs[nj] += __shfl_xor(rs[nj], 16);
      rs[nj] += __shfl_xor(rs[nj], 32);
      lreg[nj] += rs[nj];
    }

    // PV swapped: O^T[dj][o] += V^T-tile(dj) x P-tile(o)
#pragma unroll
    for (int kk = 0; kk < 2; ++kk) {
      short8 vf[4], pa[2];
#pragma unroll
      for (int dj = 0; dj < 4; ++dj) {
        const int row = dj * 16 + c;
        vf[dj] = *(const short8*)(&vs[bufi][(row * 64 + kk * 32 + g * 8) ^ ((row & 7) << 3)]);
      }
#pragma unroll
      for (int o = 0; o < 2; ++o) {
        const int row = o * 16 + c;
        pa[o] = *(const short8*)(pl + ((row * 64 + kk * 32 + g * 8) ^ ((row & 7) << 3)));
      }
#pragma unroll
      for (int dj = 0; dj < 4; ++dj)
#pragma unroll
        for (int o = 0; o < 2; ++o)
          oacc[dj][o] = __builtin_amdgcn_mfma_f32_16x16x32_bf16(vf[dj], pa[o], oacc[dj][o], 0, 0, 0);
    }
    __syncthreads();  // drains next-tile stage (vmcnt) + protects dbuf reuse
  }

  // epilogue: unnormalized O^T -> OP rows, f32x4 stores; stats from g==0 lanes
  const size_t rbase = (size_t)seg * 32768 + (size_t)bh * 2048 + q0;
#pragma unroll
  for (int o = 0; o < 2; ++o) {
    const int t = o * 16 + c;
#pragma unroll
    for (int dj = 0; dj < 4; ++dj)
      *(f32x4*)(OP + (rbase + t) * 64 + dj * 16 + g * 4) = oacc[dj][o];
    if (g == 0) {
      Mb[rbase + t] = mreg[o];
      Lb[rbase + t] = lreg[o];
    }
  }
}

// ---------------- merge: combine 4 kv-segment partials -> OB bf16 [(b*2048+t)*512 + h*64+d] ----
__global__ __launch_bounds__(256) void merge_k(const float* __restrict__ OP, const float* __restrict__ Mb,
                                               const float* __restrict__ Lb, short* __restrict__ o) {
  const int gid = blockIdx.x * 256 + threadIdx.x;  // 131072 threads
  const int row = gid >> 2;                        // bh*2048 + s
  const int dg = (gid & 3) * 16;
  float m[4], l[4];
#pragma unroll
  for (int s = 0; s < 4; ++s) { m[s] = Mb[s * 32768 + row]; l[s] = Lb[s * 32768 + row]; }
  float M = fmaxf(fmaxf(m[0], m[1]), fmaxf(m[2], m[3]));
  float w[4], L = 0.f;
#pragma unroll
  for (int s = 0; s < 4; ++s) { w[s] = __builtin_amdgcn_exp2f(m[s] - M); L += l[s] * w[s]; }
  const float rinv = 1.f / L;
  float acc[16];
#pragma unroll
  for (int j = 0; j < 16; ++j) acc[j] = 0.f;
#pragma unroll
  for (int s = 0; s < 4; ++s) {
#pragma unroll
    for (int q = 0; q < 4; ++q) {
      const f32x4 vv = *(const f32x4*)(OP + ((size_t)s * 32768 + row) * 64 + dg + q * 4);
#pragma unroll
      for (int r = 0; r < 4; ++r) acc[q * 4 + r] += vv[r] * w[s];
    }
  }
  const int bh = row >> 11, srow = row & 2047;
  const int b = bh >> 3, h = bh & 7;
  short8 st[2];
#pragma unroll
  for (int j = 0; j < 16; ++j) st[j >> 3][j & 7] = f2bf(acc[j] * rinv);
  short* dst = o + (size_t)(b * 2048 + srow) * 512 + h * 64 + dg;
  *(short8*)dst = st[0];
  *(short8*)(dst + 8) = st[1];
}

// ---------------- launcher ----------------
extern "C" void kernel_launch(void* const* d_in, const int* in_sizes, int n_in,
                              void* d_out, int out_size, void* d_ws, size_t ws_size,
                              hipStream_t stream) {
  const float* x  = (const float*)d_in[0];
  const float* wq = (const float*)d_in[1];
  const float* bq = (const float*)d_in[2];
  const float* wk = (const float*)d_in[3];
  const float* bk = (const float*)d_in[4];
  const float* wv = (const float*)d_in[5];
  const float* bv = (const float*)d_in[6];
  const float* wo = (const float*)d_in[7];
  const float* bo = (const float*)d_in[8];

  short* XT  = (short*)d_ws;                       // 4096*512 bf16
  short* WQK = XT + (size_t)4096 * 512;            // 1024*512 (wq|wk), then wv, wo contiguous
  short* WV  = WQK + (size_t)1024 * 512;
  short* WO  = WV + (size_t)512 * 512;
  short* QKB = WO + (size_t)512 * 512;             // 4096*1024
  short* VB  = QKB + (size_t)4096 * 1024;          // 512*4096
  short* OB  = VB + (size_t)512 * 4096;            // 4096*512
  float* OP  = (float*)(OB + (size_t)4096 * 512);  // 4*32768*64 f32 partial O
  float* Mb  = OP + (size_t)4 * 32768 * 64;        // 4*32768 f32
  float* Lb  = Mb + (size_t)4 * 32768;             // 4*32768 f32

  xpose_k<<<dim3(64, 16, 2), 256, 0, stream>>>(x, XT);
  wconv_k<<<dim3(1024), 256, 0, stream>>>(wq, wk, wv, wo, WQK);
  gemm_bt_k<0><<<dim3(256), 256, 0, stream>>>(WQK, XT, (void*)QKB, bq, bk);
  gemm_bt_k<1><<<dim3(128), 256, 0, stream>>>(XT, WV, (void*)VB, bv, nullptr);
  attn_k<<<dim3(16, 16, 4), 256, 0, stream>>>(QKB, VB, OP, Mb, Lb);
  merge_k<<<dim3(512), 256, 0, stream>>>(OP, Mb, Lb, OB);
  gemm_bt_k<2><<<dim3(128), 256, 0, stream>>>(OB, WO, d_out, bo, nullptr);
}

// Round 5
// 100.079 us; speedup vs baseline: 1.4890x; 1.0553x over previous
//
#include <hip/hip_runtime.h>
#include <hip/hip_bf16.h>

// MHSA: x(2,512,2048) f32, 8 heads x 64. All heavy math in bf16 MFMA 16x16x32.
// Pipeline: xpose -> wconv -> gemm_bt<0>(fused QKV) -> attn(kv-split 4) -> merge -> gemm_bt<2>(out)
// attn: swapped QK^T / swapped PV (col-t layout), K/V LDS double-buffered, o-chunked P buffer (40KB LDS -> 4 blocks/CU).

typedef __attribute__((ext_vector_type(8))) short short8;   // 8 bf16 = 4 VGPR (MFMA A/B frag)
typedef __attribute__((ext_vector_type(4))) short short4v;  // 4 bf16 (8B store)
typedef __attribute__((ext_vector_type(4))) float f32x4;    // MFMA C/D frag
typedef __attribute__((ext_vector_type(2))) int int2v;      // 8B LDS store

#define DEV static __device__ __forceinline__

DEV short f2bf(float f) {  // fp32 -> bf16 RNE
  union { float f; unsigned u; } v; v.f = f;
  unsigned r = (v.u + 0x7FFFu + ((v.u >> 16) & 1u)) >> 16;
  return (short)r;
}

DEV void gload_lds16(const void* g, void* l) {
  // wave-uniform LDS base; HW writes lane*16B
  __builtin_amdgcn_global_load_lds((const __attribute__((address_space(1))) void*)g,
                                   (__attribute__((address_space(3))) void*)l, 16, 0, 0);
}

// ---------------- pass 0a: x (B,512,2048) f32 -> XT[(b*2048+s)][512] bf16 ----------------
__global__ __launch_bounds__(256) void xpose_k(const float* __restrict__ x, short* __restrict__ xt) {
  __shared__ float tile[32][33];
  const int b = blockIdx.z;
  const int s0 = blockIdx.x * 32, c0 = blockIdx.y * 32;
  const int tl = threadIdx.x & 31, tr = threadIdx.x >> 5;  // tr 0..7
  const float* src = x + ((size_t)b * 512 + c0) * 2048 + s0;
#pragma unroll
  for (int i = 0; i < 4; ++i)
    tile[tr + i * 8][tl] = src[(size_t)(tr + i * 8) * 2048 + tl];  // tile[c][s]
  __syncthreads();
  short* dst = xt + ((size_t)b * 2048 + s0) * 512 + c0;
#pragma unroll
  for (int i = 0; i < 4; ++i) {
    const int s = tr + i * 8;
    dst[(size_t)s * 512 + tl] = f2bf(tile[tl][s]);
  }
}

// ---------------- pass 0b: weights f32 -> bf16, concat [wq|wk|wv|wo] ----------------
__global__ __launch_bounds__(256) void wconv_k(const float* __restrict__ wq, const float* __restrict__ wk,
                                               const float* __restrict__ wv, const float* __restrict__ wo,
                                               short* __restrict__ dst) {
  const int idx = blockIdx.x * 256 + threadIdx.x;  // 262144 threads, 4 elems each
  const int m = idx >> 16;
  const int base = (idx & 65535) * 4;
  const float* src = (m == 0) ? wq : (m == 1) ? wk : (m == 2) ? wv : wo;
  const f32x4 v = *(const f32x4*)(src + base);
  short4v o;
#pragma unroll
  for (int r = 0; r < 4; ++r) o[r] = f2bf(v[r]);
  *(short4v*)(dst + (size_t)idx * 4) = o;
}

// ---------------- gemm_bt: D[i][j] = sum_k A[i][k]*B[j][k], K=512, tile 128x128, BK=64 ----
// MODE 0 (fused QKV): A=Wqkv[1536][512], B=XT[4096][512], NI=12.
//   i<512: Q -> QKB[j*1024+i] scaled 1/8 +bq | 512..1023: K -> QKB[j*1024+i] +bk
//   i>=1024: V -> VB[(i-1024)*4096+j] +bv (transposed store)
// MODE 2: A=OB[4096][512], B=Wo[512][512] -> out f32 (B,512,S) (+bias0(j)), i=(b,t)
template <int MODE>
__global__ __launch_bounds__(256) void gemm_bt_k(const short* __restrict__ A, const short* __restrict__ B,
                                                 void* __restrict__ out, short* __restrict__ out2,
                                                 const float* __restrict__ bias0,
                                                 const float* __restrict__ bias1,
                                                 const float* __restrict__ bias2) {
  constexpr int NI = (MODE == 0) ? 12 : 32;
  __shared__ short As[128 * 64];
  __shared__ short Bs[128 * 64];
  const int bx = blockIdx.x;
  const int it = bx % NI, jt = bx / NI;
  const int tid = threadIdx.x;
  const int lane = tid & 63, wid = tid >> 6;
  const int wi = wid & 1, wj = wid >> 1;
  const int g = lane >> 4, c = lane & 15;

  f32x4 acc[4][4] = {};

  for (int k0 = 0; k0 < 512; k0 += 64) {
    // stage A,B tiles: pre-swizzled global source -> linear LDS; swizzled ds_read below
#pragma unroll
    for (int q = 0; q < 4; ++q) {
      const int blk = wid * 4 + q;              // 16 blocks of 8 rows
      const int row = blk * 8 + (lane >> 3);    // 0..127
      const int ks = ((lane & 7) ^ (row & 7)) * 8;
      gload_lds16(A + (size_t)(it * 128 + row) * 512 + k0 + ks, As + blk * 512);
      gload_lds16(B + (size_t)(jt * 128 + row) * 512 + k0 + ks, Bs + blk * 512);
    }
    __syncthreads();
#pragma unroll
    for (int kk = 0; kk < 2; ++kk) {
      short8 af[4], bfv[4];
#pragma unroll
      for (int mi = 0; mi < 4; ++mi) {
        const int row = wi * 64 + mi * 16 + c;
        af[mi] = *(const short8*)(As + ((row * 64 + kk * 32 + g * 8) ^ ((row & 7) << 3)));
      }
#pragma unroll
      for (int nj = 0; nj < 4; ++nj) {
        const int row = wj * 64 + nj * 16 + c;
        bfv[nj] = *(const short8*)(Bs + ((row * 64 + kk * 32 + g * 8) ^ ((row & 7) << 3)));
      }
#pragma unroll
      for (int mi = 0; mi < 4; ++mi)
#pragma unroll
        for (int nj = 0; nj < 4; ++nj)
          acc[mi][nj] = __builtin_amdgcn_mfma_f32_16x16x32_bf16(af[mi], bfv[nj], acc[mi][nj], 0, 0, 0);
    }
    __syncthreads();
  }

  // epilogue: D[i][j], lane holds rows i0+g*4+r at col j (4 consecutive i -> vector store)
  if constexpr (MODE == 0) {
    short* ob = (short*)out;
#pragma unroll
    for (int mi = 0; mi < 4; ++mi) {
      const int i0 = it * 128 + wi * 64 + mi * 16 + g * 4;  // wave-uniform range per mi
      if (i0 < 1024) {  // Q or K -> QKB[j*1024 + i]
        const bool isQ = i0 < 512;
        const float scale = isQ ? 0.125f : 1.0f;  // fold 1/sqrt(hd)=1/8 into Q
        const float* bp = isQ ? bias0 : bias1;
        const int boff = isQ ? 0 : 512;
        float b4[4];
#pragma unroll
        for (int r = 0; r < 4; ++r) b4[r] = bp[i0 + r - boff];
#pragma unroll
        for (int nj = 0; nj < 4; ++nj) {
          const int j = jt * 128 + wj * 64 + nj * 16 + c;
          short4v st;
#pragma unroll
          for (int r = 0; r < 4; ++r) st[r] = f2bf((acc[mi][nj][r] + b4[r]) * scale);
          *(short4v*)(ob + (size_t)j * 1024 + i0) = st;
        }
      } else {  // V -> VB[(i-1024)*4096 + j] (transposed scalar stores, 16-lane contiguous)
        float b4[4];
#pragma unroll
        for (int r = 0; r < 4; ++r) b4[r] = bias2[i0 + r - 1024];
#pragma unroll
        for (int nj = 0; nj < 4; ++nj) {
          const int j = jt * 128 + wj * 64 + nj * 16 + c;
#pragma unroll
          for (int r = 0; r < 4; ++r)
            out2[(size_t)(i0 + r - 1024) * 4096 + j] = f2bf(acc[mi][nj][r] + b4[r]);
        }
      }
    }
  } else {
    float* ob = (float*)out;
#pragma unroll
    for (int mi = 0; mi < 4; ++mi) {
      const int i0 = it * 128 + wi * 64 + mi * 16 + g * 4;
      const int bb = i0 >> 11, t = i0 & 2047;
#pragma unroll
      for (int nj = 0; nj < 4; ++nj) {
        const int j = jt * 128 + wj * 64 + nj * 16 + c;
        const float bj = bias0[j];
        f32x4 st;
#pragma unroll
        for (int r = 0; r < 4; ++r) st[r] = acc[mi][nj][r] + bj;
        *(f32x4*)(ob + ((size_t)(bb * 512 + j)) * 2048 + t) = st;
      }
    }
  }
}

// ---------------- attention (kv-split): per (b,h,seg), flash over 8 kv tiles of 64 ----
// QKB[(b*2048+s)*1024 + chan]: chan<512 = Q (pre-scaled 1/8), else K. VB[(h*64+d)*4096 + b*2048+s].
// Swapped layout: QK^T -> S^T (lane col t=nj*16+c), PV -> O^T (lane col t=o*16+c, rows d).
// Partials: OP[(seg*32768 + bh*2048 + row)*64 + d] f32 (unnormalized), Mb/Lb (log2-domain m).
__global__ __launch_bounds__(256, 4) void attn_k(const short* __restrict__ qk, const short* __restrict__ v,
                                                 float* __restrict__ OP, float* __restrict__ Mb,
                                                 float* __restrict__ Lb) {
  __shared__ short ks[2][64 * 64];    // K tile [s][d], swizzled      (16KB)
  __shared__ short vs[2][64 * 64];    // V tile [d][s], swizzled      (16KB)
  __shared__ short pbuf[4][16 * 64];  // per-wave P [t'][s], o-chunked (8KB)
  const int qt = blockIdx.x;          // 16 q-tiles
  const int bh = blockIdx.y;          // 16 (b,h)
  const int seg = blockIdx.z;         // 4 kv segments of 512
  const int b = bh >> 3, h = bh & 7;
  const int lane = threadIdx.x & 63, wid = threadIdx.x >> 6;
  const int g = lane >> 4, c = lane & 15;
  const int q0 = qt * 128 + wid * 32;
  short* pl = pbuf[wid];

  const short* qp = qk + (size_t)(b * 2048 + q0) * 1024 + h * 64;
  const short* kb = qk + (size_t)(b * 2048) * 1024 + 512 + h * 64;
  const short* vb = v + (size_t)(h * 64) * 4096 + b * 2048;

  // Q as B-operand frags (rows t, once per block)
  short8 qf[2][2];
#pragma unroll
  for (int nj = 0; nj < 2; ++nj)
#pragma unroll
    for (int kk = 0; kk < 2; ++kk)
      qf[nj][kk] = *(const short8*)(qp + (size_t)(nj * 16 + c) * 1024 + kk * 32 + g * 8);

  // staging geometry: row-of-8 blocks, XOR-pre-swizzled source column (16B granules)
  const int sr = lane >> 3;                 // 0..7 (== row&7)
  const int scol = ((lane & 7) ^ sr) * 8;   // shorts

  const int kvbeg = seg * 512;
  {
#pragma unroll
    for (int q = 0; q < 2; ++q) {
      const int blk = wid * 2 + q;
      const int row = blk * 8 + sr;
      gload_lds16(kb + (size_t)(kvbeg + row) * 1024 + scol, &ks[0][blk * 512]);
      gload_lds16(vb + (size_t)row * 4096 + kvbeg + scol, &vs[0][blk * 512]);
    }
  }
  __syncthreads();

  f32x4 oacc[4][2] = {};  // [dj][o]: O^T rows d=dj*16+g*4+r, col t=o*16+c
  float mreg[2] = {-1e30f, -1e30f}, lreg[2] = {0.f, 0.f};

  const float LOG2E = 1.44269504088896f;

  for (int it8 = 0; it8 < 8; ++it8) {
    const int bufi = it8 & 1;
    if (it8 < 7) {
      const int kv0 = kvbeg + (it8 + 1) * 64;
#pragma unroll
      for (int q = 0; q < 2; ++q) {
        const int blk = wid * 2 + q;
        const int row = blk * 8 + sr;
        gload_lds16(kb + (size_t)(kv0 + row) * 1024 + scol, &ks[bufi ^ 1][blk * 512]);
        gload_lds16(vb + (size_t)row * 4096 + kv0 + scol, &vs[bufi ^ 1][blk * 512]);
      }
    }

    // QK^T swapped: S^T[mi][nj], rows s=mi*16+g*4+r, col t=nj*16+c
    f32x4 st[4][2] = {};
#pragma unroll
    for (int kk = 0; kk < 2; ++kk) {
      short8 kf[4];
#pragma unroll
      for (int mi = 0; mi < 4; ++mi) {
        const int row = mi * 16 + c;
        kf[mi] = *(const short8*)(&ks[bufi][(row * 64 + kk * 32 + g * 8) ^ ((row & 7) << 3)]);
      }
#pragma unroll
      for (int mi = 0; mi < 4; ++mi)
#pragma unroll
        for (int nj = 0; nj < 2; ++nj)
          st[mi][nj] = __builtin_amdgcn_mfma_f32_16x16x32_bf16(kf[mi], qf[nj][kk], st[mi][nj], 0, 0, 0);
    }

    // V frags early (LDS latency hides under softmax)
    short8 vf[2][4];
#pragma unroll
    for (int kk = 0; kk < 2; ++kk)
#pragma unroll
      for (int dj = 0; dj < 4; ++dj) {
        const int row = dj * 16 + c;
        vf[kk][dj] = *(const short8*)(&vs[bufi][(row * 64 + kk * 32 + g * 8) ^ ((row & 7) << 3)]);
      }

    // row(t) max: lane-local 16 + 2 shuffle rounds across g-groups; scale to log2-domain
    float pm[2];
#pragma unroll
    for (int nj = 0; nj < 2; ++nj) {
      float a = fmaxf(fmaxf(st[0][nj][0], st[0][nj][1]), fmaxf(st[0][nj][2], st[0][nj][3]));
#pragma unroll
      for (int mi = 1; mi < 4; ++mi)
        a = fmaxf(a, fmaxf(fmaxf(st[mi][nj][0], st[mi][nj][1]), fmaxf(st[mi][nj][2], st[mi][nj][3])));
      a = fmaxf(a, __shfl_xor(a, 16));
      a = fmaxf(a, __shfl_xor(a, 32));
      pm[nj] = a * LOG2E;
    }
    // exact defer: if no row grows its max, sc==1 -> skip rescale entirely
    if (!__all(pm[0] <= mreg[0] && pm[1] <= mreg[1])) {
#pragma unroll
      for (int nj = 0; nj < 2; ++nj) {
        const float mnew = fmaxf(mreg[nj], pm[nj]);
        const float scf = __builtin_amdgcn_exp2f(mreg[nj] - mnew);
        mreg[nj] = mnew;
        lreg[nj] *= scf;
#pragma unroll
        for (int dj = 0; dj < 4; ++dj)
#pragma unroll
          for (int r = 0; r < 4; ++r) oacc[dj][nj][r] *= scf;
      }
    }

    // P = exp2(S*LOG2E - m), pack bf16 via f2bf (RNE) into held regs
    unsigned w0a[4][2], w1a[4][2];
    float rs[2] = {0.f, 0.f};
#pragma unroll
    for (int mi = 0; mi < 4; ++mi)
#pragma unroll
      for (int nj = 0; nj < 2; ++nj) {
        const float p0 = __builtin_amdgcn_exp2f(st[mi][nj][0] * LOG2E - mreg[nj]);
        const float p1 = __builtin_amdgcn_exp2f(st[mi][nj][1] * LOG2E - mreg[nj]);
        const float p2 = __builtin_amdgcn_exp2f(st[mi][nj][2] * LOG2E - mreg[nj]);
        const float p3 = __builtin_amdgcn_exp2f(st[mi][nj][3] * LOG2E - mreg[nj]);
        rs[nj] += (p0 + p1) + (p2 + p3);
        w0a[mi][nj] = (unsigned short)f2bf(p0) | ((unsigned)(unsigned short)f2bf(p1) << 16);
        w1a[mi][nj] = (unsigned short)f2bf(p2) | ((unsigned)(unsigned short)f2bf(p3) << 16);
      }
#pragma unroll
    for (int nj = 0; nj < 2; ++nj) {
      rs[nj] += __shfl_xor(rs[nj], 16);
      rs[nj] += __shfl_xor(rs[nj], 32);
      lreg[nj] += rs[nj];
    }

    // PV per o-half: store P rows t'=c (16x64), read as B-frag, MFMA (wave-private, no barrier)
#pragma unroll
    for (int o = 0; o < 2; ++o) {
#pragma unroll
      for (int mi = 0; mi < 4; ++mi)
        *(int2v*)(pl + ((c * 64 + mi * 16 + g * 4) ^ ((c & 7) << 3))) =
            (int2v){(int)w0a[mi][o], (int)w1a[mi][o]};
#pragma unroll
      for (int kk = 0; kk < 2; ++kk) {
        const short8 pa = *(const short8*)(pl + ((c * 64 + kk * 32 + g * 8) ^ ((c & 7) << 3)));
#pragma unroll
        for (int dj = 0; dj < 4; ++dj)
          oacc[dj][o] = __builtin_amdgcn_mfma_f32_16x16x32_bf16(vf[kk][dj], pa, oacc[dj][o], 0, 0, 0);
      }
    }
    __syncthreads();  // drains next-tile stage (vmcnt) + protects dbuf reuse
  }

  // epilogue: unnormalized O^T -> OP rows, f32x4 stores; stats from g==0 lanes
  const size_t rbase = (size_t)seg * 32768 + (size_t)bh * 2048 + q0;
#pragma unroll
  for (int o = 0; o < 2; ++o) {
    const int t = o * 16 + c;
#pragma unroll
    for (int dj = 0; dj < 4; ++dj)
      *(f32x4*)(OP + (rbase + t) * 64 + dj * 16 + g * 4) = oacc[dj][o];
    if (g == 0) {
      Mb[rbase + t] = mreg[o];
      Lb[rbase + t] = lreg[o];
    }
  }
}

// ---------------- merge: combine 4 kv-segment partials -> OB bf16 [(b*2048+t)*512 + h*64+d] ----
__global__ __launch_bounds__(256) void merge_k(const float* __restrict__ OP, const float* __restrict__ Mb,
                                               const float* __restrict__ Lb, short* __restrict__ o) {
  const int gid = blockIdx.x * 256 + threadIdx.x;  // 131072 threads
  const int row = gid >> 2;                        // bh*2048 + s
  const int dg = (gid & 3) * 16;
  float m[4], l[4];
#pragma unroll
  for (int s = 0; s < 4; ++s) { m[s] = Mb[s * 32768 + row]; l[s] = Lb[s * 32768 + row]; }
  float M = fmaxf(fmaxf(m[0], m[1]), fmaxf(m[2], m[3]));
  float w[4], L = 0.f;
#pragma unroll
  for (int s = 0; s < 4; ++s) { w[s] = __builtin_amdgcn_exp2f(m[s] - M); L += l[s] * w[s]; }
  const float rinv = 1.f / L;
  float acc[16];
#pragma unroll
  for (int j = 0; j < 16; ++j) acc[j] = 0.f;
#pragma unroll
  for (int s = 0; s < 4; ++s) {
#pragma unroll
    for (int q = 0; q < 4; ++q) {
      const f32x4 vv = *(const f32x4*)(OP + ((size_t)s * 32768 + row) * 64 + dg + q * 4);
#pragma unroll
      for (int r = 0; r < 4; ++r) acc[q * 4 + r] += vv[r] * w[s];
    }
  }
  const int bh = row >> 11, srow = row & 2047;
  const int b = bh >> 3, h = bh & 7;
  short8 st[2];
#pragma unroll
  for (int j = 0; j < 16; ++j) st[j >> 3][j & 7] = f2bf(acc[j] * rinv);
  short* dst = o + (size_t)(b * 2048 + srow) * 512 + h * 64 + dg;
  *(short8*)dst = st[0];
  *(short8*)(dst + 8) = st[1];
}

// ---------------- launcher ----------------
extern "C" void kernel_launch(void* const* d_in, const int* in_sizes, int n_in,
                              void* d_out, int out_size, void* d_ws, size_t ws_size,
                              hipStream_t stream) {
  const float* x  = (const float*)d_in[0];
  const float* wq = (const float*)d_in[1];
  const float* bq = (const float*)d_in[2];
  const float* wk = (const float*)d_in[3];
  const float* bk = (const float*)d_in[4];
  const float* wv = (const float*)d_in[5];
  const float* bv = (const float*)d_in[6];
  const float* wo = (const float*)d_in[7];
  const float* bo = (const float*)d_in[8];

  short* XT  = (short*)d_ws;                       // 4096*512 bf16
  short* WQKV = XT + (size_t)4096 * 512;           // 1536*512 (wq|wk|wv)
  short* WO  = WQKV + (size_t)1536 * 512;          // 512*512
  short* QKB = WO + (size_t)512 * 512;             // 4096*1024
  short* VB  = QKB + (size_t)4096 * 1024;          // 512*4096
  short* OB  = VB + (size_t)512 * 4096;            // 4096*512
  float* OP  = (float*)(OB + (size_t)4096 * 512);  // 4*32768*64 f32 partial O
  float* Mb  = OP + (size_t)4 * 32768 * 64;        // 4*32768 f32
  float* Lb  = Mb + (size_t)4 * 32768;             // 4*32768 f32

  xpose_k<<<dim3(64, 16, 2), 256, 0, stream>>>(x, XT);
  wconv_k<<<dim3(1024), 256, 0, stream>>>(wq, wk, wv, wo, WQKV);
  gemm_bt_k<0><<<dim3(384), 256, 0, stream>>>(WQKV, XT, (void*)QKB, VB, bq, bk, bv);
  attn_k<<<dim3(16, 16, 4), 256, 0, stream>>>(QKB, VB, OP, Mb, Lb);
  merge_k<<<dim3(512), 256, 0, stream>>>(OP, Mb, Lb, OB);
  gemm_bt_k<2><<<dim3(128), 256, 0, stream>>>(OB, WO, d_out, nullptr, bo, nullptr, nullptr);
}

// Round 6
// 94.602 us; speedup vs baseline: 1.5752x; 1.0579x over previous
//
#include <hip/hip_runtime.h>
#include <hip/hip_bf16.h>

// MHSA: x(2,512,2048) f32, 8 heads x 64. All heavy math in bf16 MFMA 16x16x32.
// Pipeline: xpose -> wconv -> gemm_bt<0>(fused QKV) -> attn(kv-split 4) -> merge -> gemm_bt<2>(out)
// attn: XCD-swizzled blocks; swapped QK^T/PV; K dbuf + V single-buf early-issue (counted vmcnt + raw barrier);
//       full per-wave P buffer; 40KB LDS -> 4 blocks/CU.

typedef __attribute__((ext_vector_type(8))) short short8;   // 8 bf16 = 4 VGPR (MFMA A/B frag)
typedef __attribute__((ext_vector_type(4))) short short4v;  // 4 bf16 (8B store)
typedef __attribute__((ext_vector_type(4))) float f32x4;    // MFMA C/D frag
typedef __attribute__((ext_vector_type(2))) int int2v;      // 8B LDS store

#define DEV static __device__ __forceinline__

DEV short f2bf(float f) {  // fp32 -> bf16 RNE
  union { float f; unsigned u; } v; v.f = f;
  unsigned r = (v.u + 0x7FFFu + ((v.u >> 16) & 1u)) >> 16;
  return (short)r;
}

DEV void gload_lds16(const void* g, void* l) {
  // wave-uniform LDS base; HW writes lane*16B
  __builtin_amdgcn_global_load_lds((const __attribute__((address_space(1))) void*)g,
                                   (__attribute__((address_space(3))) void*)l, 16, 0, 0);
}

// ---------------- pass 0a: x (B,512,2048) f32 -> XT[(b*2048+s)][512] bf16 ----------------
__global__ __launch_bounds__(256) void xpose_k(const float* __restrict__ x, short* __restrict__ xt) {
  __shared__ float tile[32][33];
  const int b = blockIdx.z;
  const int s0 = blockIdx.x * 32, c0 = blockIdx.y * 32;
  const int tl = threadIdx.x & 31, tr = threadIdx.x >> 5;  // tr 0..7
  const float* src = x + ((size_t)b * 512 + c0) * 2048 + s0;
#pragma unroll
  for (int i = 0; i < 4; ++i)
    tile[tr + i * 8][tl] = src[(size_t)(tr + i * 8) * 2048 + tl];  // tile[c][s]
  __syncthreads();
  short* dst = xt + ((size_t)b * 2048 + s0) * 512 + c0;
#pragma unroll
  for (int i = 0; i < 4; ++i) {
    const int s = tr + i * 8;
    dst[(size_t)s * 512 + tl] = f2bf(tile[tl][s]);
  }
}

// ---------------- pass 0b: weights f32 -> bf16, concat [wq|wk|wv|wo] ----------------
__global__ __launch_bounds__(256) void wconv_k(const float* __restrict__ wq, const float* __restrict__ wk,
                                               const float* __restrict__ wv, const float* __restrict__ wo,
                                               short* __restrict__ dst) {
  const int idx = blockIdx.x * 256 + threadIdx.x;  // 262144 threads, 4 elems each
  const int m = idx >> 16;
  const int base = (idx & 65535) * 4;
  const float* src = (m == 0) ? wq : (m == 1) ? wk : (m == 2) ? wv : wo;
  const f32x4 v = *(const f32x4*)(src + base);
  short4v o;
#pragma unroll
  for (int r = 0; r < 4; ++r) o[r] = f2bf(v[r]);
  *(short4v*)(dst + (size_t)idx * 4) = o;
}

// ---------------- gemm_bt: D[i][j] = sum_k A[i][k]*B[j][k], K=512, tile 128x128, BK=64 ----
// MODE 0 (fused QKV): A=Wqkv[1536][512], B=XT[4096][512], NI=12, grid 384 (XCD-swizzled).
//   i<512: Q -> QKB[j*1024+i] scaled 1/8 +bq | 512..1023: K -> QKB[j*1024+i] +bk
//   i>=1024: V -> VB[(i-1024)*4096+j] +bv (transposed store)
// MODE 2: A=OB[4096][512], B=Wo[512][512] -> out f32 (B,512,S) (+bias0(j)), i=(b,t), grid 128 (swizzled)
template <int MODE>
__global__ __launch_bounds__(256) void gemm_bt_k(const short* __restrict__ A, const short* __restrict__ B,
                                                 void* __restrict__ out, short* __restrict__ out2,
                                                 const float* __restrict__ bias0,
                                                 const float* __restrict__ bias1,
                                                 const float* __restrict__ bias2) {
  constexpr int NI = (MODE == 0) ? 12 : 32;
  constexpr int CHUNK = (MODE == 0) ? 48 : 16;  // gridDim/8, grid % 8 == 0
  __shared__ short As[128 * 64];
  __shared__ short Bs[128 * 64];
  const int bx0 = blockIdx.x;
  const int bx = (bx0 & 7) * CHUNK + (bx0 >> 3);  // XCD-contiguous chunks
  const int it = bx % NI, jt = bx / NI;
  const int tid = threadIdx.x;
  const int lane = tid & 63, wid = tid >> 6;
  const int wi = wid & 1, wj = wid >> 1;
  const int g = lane >> 4, c = lane & 15;

  f32x4 acc[4][4] = {};

  for (int k0 = 0; k0 < 512; k0 += 64) {
    // stage A,B tiles: pre-swizzled global source -> linear LDS; swizzled ds_read below
#pragma unroll
    for (int q = 0; q < 4; ++q) {
      const int blk = wid * 4 + q;              // 16 blocks of 8 rows
      const int row = blk * 8 + (lane >> 3);    // 0..127
      const int ks = ((lane & 7) ^ (row & 7)) * 8;
      gload_lds16(A + (size_t)(it * 128 + row) * 512 + k0 + ks, As + blk * 512);
      gload_lds16(B + (size_t)(jt * 128 + row) * 512 + k0 + ks, Bs + blk * 512);
    }
    __syncthreads();
#pragma unroll
    for (int kk = 0; kk < 2; ++kk) {
      short8 af[4], bfv[4];
#pragma unroll
      for (int mi = 0; mi < 4; ++mi) {
        const int row = wi * 64 + mi * 16 + c;
        af[mi] = *(const short8*)(As + ((row * 64 + kk * 32 + g * 8) ^ ((row & 7) << 3)));
      }
#pragma unroll
      for (int nj = 0; nj < 4; ++nj) {
        const int row = wj * 64 + nj * 16 + c;
        bfv[nj] = *(const short8*)(Bs + ((row * 64 + kk * 32 + g * 8) ^ ((row & 7) << 3)));
      }
#pragma unroll
      for (int mi = 0; mi < 4; ++mi)
#pragma unroll
        for (int nj = 0; nj < 4; ++nj)
          acc[mi][nj] = __builtin_amdgcn_mfma_f32_16x16x32_bf16(af[mi], bfv[nj], acc[mi][nj], 0, 0, 0);
    }
    __syncthreads();
  }

  // epilogue: D[i][j], lane holds rows i0+g*4+r at col j (4 consecutive i -> vector store)
  if constexpr (MODE == 0) {
    short* ob = (short*)out;
#pragma unroll
    for (int mi = 0; mi < 4; ++mi) {
      const int i0 = it * 128 + wi * 64 + mi * 16 + g * 4;  // wave-uniform range per mi
      if (i0 < 1024) {  // Q or K -> QKB[j*1024 + i]
        const bool isQ = i0 < 512;
        const float scale = isQ ? 0.125f : 1.0f;  // fold 1/sqrt(hd)=1/8 into Q
        const float* bp = isQ ? bias0 : bias1;
        const int boff = isQ ? 0 : 512;
        float b4[4];
#pragma unroll
        for (int r = 0; r < 4; ++r) b4[r] = bp[i0 + r - boff];
#pragma unroll
        for (int nj = 0; nj < 4; ++nj) {
          const int j = jt * 128 + wj * 64 + nj * 16 + c;
          short4v st;
#pragma unroll
          for (int r = 0; r < 4; ++r) st[r] = f2bf((acc[mi][nj][r] + b4[r]) * scale);
          *(short4v*)(ob + (size_t)j * 1024 + i0) = st;
        }
      } else {  // V -> VB[(i-1024)*4096 + j] (transposed scalar stores, 16-lane contiguous)
        float b4[4];
#pragma unroll
        for (int r = 0; r < 4; ++r) b4[r] = bias2[i0 + r - 1024];
#pragma unroll
        for (int nj = 0; nj < 4; ++nj) {
          const int j = jt * 128 + wj * 64 + nj * 16 + c;
#pragma unroll
          for (int r = 0; r < 4; ++r)
            out2[(size_t)(i0 + r - 1024) * 4096 + j] = f2bf(acc[mi][nj][r] + b4[r]);
        }
      }
    }
  } else {
    float* ob = (float*)out;
#pragma unroll
    for (int mi = 0; mi < 4; ++mi) {
      const int i0 = it * 128 + wi * 64 + mi * 16 + g * 4;
      const int bb = i0 >> 11, t = i0 & 2047;
#pragma unroll
      for (int nj = 0; nj < 4; ++nj) {
        const int j = jt * 128 + wj * 64 + nj * 16 + c;
        const float bj = bias0[j];
        f32x4 st;
#pragma unroll
        for (int r = 0; r < 4; ++r) st[r] = acc[mi][nj][r] + bj;
        *(f32x4*)(ob + ((size_t)(bb * 512 + j)) * 2048 + t) = st;
      }
    }
  }
}

// ---------------- attention (kv-split): per (b,h,seg), flash over 8 kv tiles of 64 ----
// Grid 1D 1024, XCD-swizzled so the 16 qt-blocks sharing a (bh,seg) K/V slice land on ONE XCD.
// QKB[(b*2048+s)*1024 + chan]: chan<512 = Q (pre-scaled 1/8), else K. VB[(h*64+d)*4096 + b*2048+s].
// Swapped layout: QK^T -> S^T (lane col t=nj*16+c), PV -> O^T (lane col t=o*16+c, rows d).
// Partials: OP[(seg*32768 + bh*2048 + row)*64 + d] f32 (unnormalized), Mb/Lb (log2-domain m).
__global__ __launch_bounds__(256, 4) void attn_k(const short* __restrict__ qk, const short* __restrict__ v,
                                                 float* __restrict__ OP, float* __restrict__ Mb,
                                                 float* __restrict__ Lb) {
  __shared__ short ks2[2][64 * 64];   // K tile [s][d], swizzled, double-buffered (16KB)
  __shared__ short vs[64 * 64];       // V tile [d][s], swizzled, single buffer    (8KB)
  __shared__ short pbuf[4][32 * 64];  // per-wave P [t][s], swizzled              (16KB)
  const int bid = blockIdx.x;                       // 0..1023
  const int swz = (bid & 7) * 128 + (bid >> 3);     // XCD-contiguous chunks of 128
  const int qt = swz & 15;                          // fastest within chunk
  const int grp = swz >> 4;                         // (bh,seg) group, 8 per XCD
  const int bh = grp & 15, seg = grp >> 4;
  const int b = bh >> 3, h = bh & 7;
  const int lane = threadIdx.x & 63, wid = threadIdx.x >> 6;
  const int g = lane >> 4, c = lane & 15;
  const int q0 = qt * 128 + wid * 32;
  short* pl = pbuf[wid];

  const short* qp = qk + (size_t)(b * 2048 + q0) * 1024 + h * 64;
  const short* kb = qk + (size_t)(b * 2048) * 1024 + 512 + h * 64;
  const short* vb = v + (size_t)(h * 64) * 4096 + b * 2048;

  // Q as B-operand frags (rows t, once per block)
  short8 qf[2][2];
#pragma unroll
  for (int nj = 0; nj < 2; ++nj)
#pragma unroll
    for (int kk = 0; kk < 2; ++kk)
      qf[nj][kk] = *(const short8*)(qp + (size_t)(nj * 16 + c) * 1024 + kk * 32 + g * 8);

  // staging geometry: row-of-8 blocks, XOR-pre-swizzled source column (16B granules)
  const int sr = lane >> 3;                 // 0..7 (== row&7)
  const int scol = ((lane & 7) ^ sr) * 8;   // shorts

  const int kvbeg = seg * 512;
  {
#pragma unroll
    for (int q = 0; q < 2; ++q) {
      const int blk = wid * 2 + q;
      const int row = blk * 8 + sr;
      gload_lds16(vb + (size_t)row * 4096 + kvbeg + scol, &vs[blk * 512]);
      gload_lds16(kb + (size_t)(kvbeg + row) * 1024 + scol, &ks2[0][blk * 512]);
    }
  }
  __syncthreads();

  f32x4 oacc[4][2] = {};  // [dj][o]: O^T rows d=dj*16+g*4+r, col t=o*16+c
  float mreg[2] = {-1e30f, -1e30f}, lreg[2] = {0.f, 0.f};

  const float LOG2E = 1.44269504088896f;

  for (int it8 = 0; it8 < 8; ++it8) {
    const int bufi = it8 & 1;
    // issue V[it8] (oldest, for THIS iter; it8==0 already staged) then K[next] (dbuf prefetch)
    if (it8 > 0) {
      const int kv0 = kvbeg + it8 * 64;
#pragma unroll
      for (int q = 0; q < 2; ++q) {
        const int blk = wid * 2 + q;
        const int row = blk * 8 + sr;
        gload_lds16(vb + (size_t)row * 4096 + kv0 + scol, &vs[blk * 512]);
      }
    }
    {
      const int kvn = kvbeg + ((it8 + 1) & 7) * 64;  // wrapped: count-invariant prefetch
#pragma unroll
      for (int q = 0; q < 2; ++q) {
        const int blk = wid * 2 + q;
        const int row = blk * 8 + sr;
        gload_lds16(kb + (size_t)(kvn + row) * 1024 + scol, &ks2[bufi ^ 1][blk * 512]);
      }
    }

    // QK^T swapped: S^T[mi][nj], rows s=mi*16+g*4+r, col t=nj*16+c
    f32x4 st[4][2] = {};
#pragma unroll
    for (int kk = 0; kk < 2; ++kk) {
      short8 kf[4];
#pragma unroll
      for (int mi = 0; mi < 4; ++mi) {
        const int row = mi * 16 + c;
        kf[mi] = *(const short8*)(&ks2[bufi][(row * 64 + kk * 32 + g * 8) ^ ((row & 7) << 3)]);
      }
#pragma unroll
      for (int mi = 0; mi < 4; ++mi)
#pragma unroll
        for (int nj = 0; nj < 2; ++nj)
          st[mi][nj] = __builtin_amdgcn_mfma_f32_16x16x32_bf16(kf[mi], qf[nj][kk], st[mi][nj], 0, 0, 0);
    }

    // row(t) max: lane-local 16 + 2 shuffle rounds across g-groups; scale to log2-domain
    float pm[2];
#pragma unroll
    for (int nj = 0; nj < 2; ++nj) {
      float a = fmaxf(fmaxf(st[0][nj][0], st[0][nj][1]), fmaxf(st[0][nj][2], st[0][nj][3]));
#pragma unroll
      for (int mi = 1; mi < 4; ++mi)
        a = fmaxf(a, fmaxf(fmaxf(st[mi][nj][0], st[mi][nj][1]), fmaxf(st[mi][nj][2], st[mi][nj][3])));
      a = fmaxf(a, __shfl_xor(a, 16));
      a = fmaxf(a, __shfl_xor(a, 32));
      pm[nj] = a * LOG2E;
    }
    // exact defer: if no row grows its max, sc==1 -> skip rescale entirely
    if (!__all(pm[0] <= mreg[0] && pm[1] <= mreg[1])) {
#pragma unroll
      for (int nj = 0; nj < 2; ++nj) {
        const float mnew = fmaxf(mreg[nj], pm[nj]);
        const float scf = __builtin_amdgcn_exp2f(mreg[nj] - mnew);
        mreg[nj] = mnew;
        lreg[nj] *= scf;
#pragma unroll
        for (int dj = 0; dj < 4; ++dj)
#pragma unroll
          for (int r = 0; r < 4; ++r) oacc[dj][nj][r] *= scf;
      }
    }

    // P = exp2(S*LOG2E - m), pack bf16 via f2bf (RNE), swizzled 8B stores to pbuf[t][s]
    float rs[2] = {0.f, 0.f};
#pragma unroll
    for (int mi = 0; mi < 4; ++mi)
#pragma unroll
      for (int nj = 0; nj < 2; ++nj) {
        const float p0 = __builtin_amdgcn_exp2f(st[mi][nj][0] * LOG2E - mreg[nj]);
        const float p1 = __builtin_amdgcn_exp2f(st[mi][nj][1] * LOG2E - mreg[nj]);
        const float p2 = __builtin_amdgcn_exp2f(st[mi][nj][2] * LOG2E - mreg[nj]);
        const float p3 = __builtin_amdgcn_exp2f(st[mi][nj][3] * LOG2E - mreg[nj]);
        rs[nj] += (p0 + p1) + (p2 + p3);
        const unsigned w0 = (unsigned short)f2bf(p0) | ((unsigned)(unsigned short)f2bf(p1) << 16);
        const unsigned w1 = (unsigned short)f2bf(p2) | ((unsigned)(unsigned short)f2bf(p3) << 16);
        const int t = nj * 16 + c;
        *(int2v*)(pl + ((t * 64 + mi * 16 + g * 4) ^ ((t & 7) << 3))) = (int2v){(int)w0, (int)w1};
      }
#pragma unroll
    for (int nj = 0; nj < 2; ++nj) {
      rs[nj] += __shfl_xor(rs[nj], 16);
      rs[nj] += __shfl_xor(rs[nj], 32);
      lreg[nj] += rs[nj];
    }

    // V[it8] ready: this wave's V loads are the 2 OLDEST of 4 in-flight -> vmcnt(2); raw barrier
    asm volatile("s_waitcnt vmcnt(2)" ::: "memory");
    __builtin_amdgcn_s_barrier();

    // PV swapped: O^T[dj][o] += V^T-tile(dj) x P-tile(o)
#pragma unroll
    for (int kk = 0; kk < 2; ++kk) {
      short8 vf[4], pa[2];
#pragma unroll
      for (int dj = 0; dj < 4; ++dj) {
        const int row = dj * 16 + c;
        vf[dj] = *(const short8*)(&vs[(row * 64 + kk * 32 + g * 8) ^ ((row & 7) << 3)]);
      }
#pragma unroll
      for (int o = 0; o < 2; ++o) {
        const int row = o * 16 + c;
        pa[o] = *(const short8*)(pl + ((row * 64 + kk * 32 + g * 8) ^ ((row & 7) << 3)));
      }
#pragma unroll
      for (int dj = 0; dj < 4; ++dj)
#pragma unroll
        for (int o = 0; o < 2; ++o)
          oacc[dj][o] = __builtin_amdgcn_mfma_f32_16x16x32_bf16(vf[dj], pa[o], oacc[dj][o], 0, 0, 0);
    }
    __syncthreads();  // all PV reads done -> next iter may overwrite vs; drains K prefetch
  }

  // epilogue: unnormalized O^T -> OP rows, f32x4 stores; stats from g==0 lanes
  const size_t rbase = (size_t)seg * 32768 + (size_t)bh * 2048 + q0;
#pragma unroll
  for (int o = 0; o < 2; ++o) {
    const int t = o * 16 + c;
#pragma unroll
    for (int dj = 0; dj < 4; ++dj)
      *(f32x4*)(OP + (rbase + t) * 64 + dj * 16 + g * 4) = oacc[dj][o];
    if (g == 0) {
      Mb[rbase + t] = mreg[o];
      Lb[rbase + t] = lreg[o];
    }
  }
}

// ---------------- merge: combine 4 kv-segment partials -> OB bf16 [(b*2048+t)*512 + h*64+d] ----
__global__ __launch_bounds__(256) void merge_k(const float* __restrict__ OP, const float* __restrict__ Mb,
                                               const float* __restrict__ Lb, short* __restrict__ o) {
  const int gid = blockIdx.x * 256 + threadIdx.x;  // 131072 threads
  const int row = gid >> 2;                        // bh*2048 + s
  const int dg = (gid & 3) * 16;
  float m[4], l[4];
#pragma unroll
  for (int s = 0; s < 4; ++s) { m[s] = Mb[s * 32768 + row]; l[s] = Lb[s * 32768 + row]; }
  float M = fmaxf(fmaxf(m[0], m[1]), fmaxf(m[2], m[3]));
  float w[4], L = 0.f;
#pragma unroll
  for (int s = 0; s < 4; ++s) { w[s] = __builtin_amdgcn_exp2f(m[s] - M); L += l[s] * w[s]; }
  const float rinv = 1.f / L;
  float acc[16];
#pragma unroll
  for (int j = 0; j < 16; ++j) acc[j] = 0.f;
#pragma unroll
  for (int s = 0; s < 4; ++s) {
#pragma unroll
    for (int q = 0; q < 4; ++q) {
      const f32x4 vv = *(const f32x4*)(OP + ((size_t)s * 32768 + row) * 64 + dg + q * 4);
#pragma unroll
      for (int r = 0; r < 4; ++r) acc[q * 4 + r] += vv[r] * w[s];
    }
  }
  const int bh = row >> 11, srow = row & 2047;
  const int b = bh >> 3, h = bh & 7;
  short8 st[2];
#pragma unroll
  for (int j = 0; j < 16; ++j) st[j >> 3][j & 7] = f2bf(acc[j] * rinv);
  short* dst = o + (size_t)(b * 2048 + srow) * 512 + h * 64 + dg;
  *(short8*)dst = st[0];
  *(short8*)(dst + 8) = st[1];
}

// ---------------- launcher ----------------
extern "C" void kernel_launch(void* const* d_in, const int* in_sizes, int n_in,
                              void* d_out, int out_size, void* d_ws, size_t ws_size,
                              hipStream_t stream) {
  const float* x  = (const float*)d_in[0];
  const float* wq = (const float*)d_in[1];
  const float* bq = (const float*)d_in[2];
  const float* wk = (const float*)d_in[3];
  const float* bk = (const float*)d_in[4];
  const float* wv = (const float*)d_in[5];
  const float* bv = (const float*)d_in[6];
  const float* wo = (const float*)d_in[7];
  const float* bo = (const float*)d_in[8];

  short* XT  = (short*)d_ws;                       // 4096*512 bf16
  short* WQKV = XT + (size_t)4096 * 512;           // 1536*512 (wq|wk|wv)
  short* WO  = WQKV + (size_t)1536 * 512;          // 512*512
  short* QKB = WO + (size_t)512 * 512;             // 4096*1024
  short* VB  = QKB + (size_t)4096 * 1024;          // 512*4096
  short* OB  = VB + (size_t)512 * 4096;            // 4096*512
  float* OP  = (float*)(OB + (size_t)4096 * 512);  // 4*32768*64 f32 partial O
  float* Mb  = OP + (size_t)4 * 32768 * 64;        // 4*32768 f32
  float* Lb  = Mb + (size_t)4 * 32768;             // 4*32768 f32

  xpose_k<<<dim3(64, 16, 2), 256, 0, stream>>>(x, XT);
  wconv_k<<<dim3(1024), 256, 0, stream>>>(wq, wk, wv, wo, WQKV);
  gemm_bt_k<0><<<dim3(384), 256, 0, stream>>>(WQKV, XT, (void*)QKB, VB, bq, bk, bv);
  attn_k<<<dim3(1024), 256, 0, stream>>>(QKB, VB, OP, Mb, Lb);
  merge_k<<<dim3(512), 256, 0, stream>>>(OP, Mb, Lb, OB);
  gemm_bt_k<2><<<dim3(128), 256, 0, stream>>>(OB, WO, d_out, nullptr, bo, nullptr, nullptr);
}